// Round 10
// baseline (65.014 us; speedup 1.0000x reference)
//
#include <hip/hip_runtime.h>
#include <math.h>

static constexpr int BLOCK = 256;
static constexpr int WAVES = BLOCK / 64;
static constexpr int KVAL = 4;
static constexpr int TILE = 256;  // vertices per s1 block

typedef float f4 __attribute__((ext_vector_type(4)));
typedef int i4 __attribute__((ext_vector_type(4)));
typedef unsigned int u4v __attribute__((ext_vector_type(4)));
union VV { u4v u4; _Float16 h[8]; };
union PQ { u4v u[3]; _Float16 h[24]; };

// LDS float offsets (TILE=256): pg 0 | g 768 | ng 1536 | uu 2304 | vv 3072 |
// hh 3840(2304) | rr 6144(9216)  -> total 15360 floats = 60 KB
static constexpr int L_PG = 0, L_G = 768, L_NG = 1536, L_U = 2304, L_V = 3072,
                     L_H = 3840, L_R = 6144, L_TOT = 15360;

__device__ __forceinline__ void gld_lds16(const void* g, void* l) {
  __builtin_amdgcn_global_load_lds(
      (const __attribute__((address_space(1))) void*)g,
      (__attribute__((address_space(3))) void*)l, 16, 0, 0);
}

__device__ __forceinline__ void norm3(float x, float y, float z,
                                      float& ox, float& oy, float& oz) {
  float inv = 1.0f / (sqrtf(x * x + y * y + z * z) + 1e-12f);
  ox = x * inv; oy = y * inv; oz = z * inv;
}

template <int NV>
__device__ __forceinline__ void block_reduce(float (&p)[NV]) {
#pragma unroll
  for (int off = 32; off > 0; off >>= 1)
#pragma unroll
    for (int q = 0; q < NV; ++q) p[q] += __shfl_down(p[q], off, 64);
  __shared__ float sm[WAVES][NV];
  int wave = threadIdx.x >> 6, lane = threadIdx.x & 63;
  if (lane == 0)
#pragma unroll
    for (int q = 0; q < NV; ++q) sm[wave][q] = p[q];
  __syncthreads();
  if (threadIdx.x == 0) {
#pragma unroll
    for (int q = 0; q < NV; ++q) {
      float t = 0.f;
#pragma unroll
      for (int w = 1; w < WAVES; ++w) t += sm[w][q];
      p[q] += t;
    }
  }
}

__device__ __forceinline__ void stage_f(float* __restrict__ dst,
                                        const float* __restrict__ src, int nf) {
  int t = threadIdx.x;
  int nf4 = nf >> 2;
  const f4* s4 = (const f4*)src;
  f4* d4 = (f4*)dst;
  for (int i = t; i < nf4; i += BLOCK) d4[i] = s4[i];
  int rem = nf & 3;
  if (t < rem) dst[nf4 * 4 + t] = src[nf4 * 4 + t];
}

// ---- S1: all streaming terms; single async-staged burst, one barrier -------
__global__ __launch_bounds__(BLOCK) void s1_kernel(
    const float* __restrict__ theta, const float* __restrict__ u,
    const float* __restrict__ v, u4v* __restrict__ vavb,
    u4v* __restrict__ pq0, u4v* __restrict__ pq1, u4v* __restrict__ pq2, int N,
    const float* __restrict__ pred, const float* __restrict__ pgrad,
    const float* __restrict__ mp, const float* __restrict__ grad,
    const float* __restrict__ H, const float* __restrict__ ngt,
    const float* __restrict__ rot,
    float* __restrict__ part1, int nb1, int M) {
  __shared__ float B[L_TOT];
  int t = threadIdx.x;
  long base = (long)blockIdx.x * TILE;
  float p[5] = {0.f, 0.f, 0.f, 0.f, 0.f};  // sdf, eik, morse, halign, inter

  int cntM = 0, cntN = 0;
  if (base < M) { long c = (long)M - base; cntM = c > TILE ? TILE : (int)c; }
  if (base < N) { long c = (long)N - base; cntN = c > TILE ? TILE : (int)c; }

  // stride-1 streams -> registers (coalesced), issued before the DMA burst
  float prv = 0.f, mpv = 0.f, thv = 0.f;
  if (t < cntM) prv = pred[base + t];
  if (t < cntN) { mpv = mp[base + t]; thv = theta[base + t]; }

  bool full = (cntM == TILE) && (cntN == TILE);
  if (full) {
    // 60 x 1KB async DMA chunks, round-robin across 4 waves
    int wave = t >> 6, lane = t & 63;
    const float* srcs[7] = {pgrad + 3 * base, grad + 3 * base, ngt + 3 * base,
                            u + 3 * base,     v + 3 * base,    H + 9 * base,
                            rot + 36 * base};
    const int foff[7] = {L_PG, L_G, L_NG, L_U, L_V, L_H, L_R};
    const int nchk[7] = {3, 3, 3, 3, 3, 9, 36};
    int c = wave, cs = 0;
#pragma unroll
    for (int s = 0; s < 7; ++s) {
      while (c < cs + nchk[s]) {
        int boff = (c - cs) * 1024;
        gld_lds16((const char*)srcs[s] + boff + lane * 16,
                  (char*)&B[foff[s]] + boff);
        c += WAVES;
      }
      cs += nchk[s];
    }
  } else {
    if (cntM > 0) stage_f(B + L_PG, pgrad + 3 * base, 3 * cntM);
    if (cntN > 0) {
      stage_f(B + L_G, grad + 3 * base, 3 * cntN);
      stage_f(B + L_NG, ngt + 3 * base, 3 * cntN);
      stage_f(B + L_U, u + 3 * base, 3 * cntN);
      stage_f(B + L_V, v + 3 * base, 3 * cntN);
      stage_f(B + L_H, H + 9 * base, 9 * cntN);
      stage_f(B + L_R, rot + 36 * base, 36 * cntN);
    }
  }
  __syncthreads();  // drains vmcnt(0): all DMA chunks landed

  if (t < cntM) {
    float gx = B[L_PG + 3 * t], gy = B[L_PG + 3 * t + 1], gz = B[L_PG + 3 * t + 2];
    p[1] += fabsf(sqrtf(gx * gx + gy * gy + gz * gz) - 1.0f);
    p[4] += __expf(-100.0f * fabsf(prv));
  }
  if (t < cntN) {
    long i = base + t;
    p[0] = fabsf(mpv);
    float gx = B[L_G + 3 * t], gy = B[L_G + 3 * t + 1], gz = B[L_G + 3 * t + 2];
    p[1] += fabsf(sqrtf(gx * gx + gy * gy + gz * gz) - 1.0f);

    float s, cth;
    __sincosf(thv, &s, &cth);
    float ux = B[L_U + 3 * t], uy = B[L_U + 3 * t + 1], uz = B[L_U + 3 * t + 2];
    float vx = B[L_V + 3 * t], vy = B[L_V + 3 * t + 1], vz = B[L_V + 3 * t + 2];
    float va[3], vb[3];
    norm3(ux * cth + vx * s, uy * cth + vy * s, uz * cth + vz * s,
          va[0], va[1], va[2]);
    norm3(vx * cth - ux * s, vy * cth - uy * s, vz * cth - uz * s,
          vb[0], vb[1], vb[2]);
    VV o;
    o.h[0] = (_Float16)va[0]; o.h[1] = (_Float16)va[1]; o.h[2] = (_Float16)va[2];
    o.h[3] = (_Float16)vb[0]; o.h[4] = (_Float16)vb[1]; o.h[5] = (_Float16)vb[2];
    o.h[6] = (_Float16)0.f;   o.h[7] = (_Float16)0.f;
    vavb[i] = o.u4;

    float h[9];
#pragma unroll
    for (int q = 0; q < 9; ++q) h[q] = B[L_H + 9 * t + q];
    float n0 = B[L_NG + 3 * t], n1 = B[L_NG + 3 * t + 1], n2 = B[L_NG + 3 * t + 2];
    p[2] = fabsf(n0 * h[0] + n1 * h[3] + n2 * h[6]) +
           fabsf(n0 * h[1] + n1 * h[4] + n2 * h[7]) +
           fabsf(n0 * h[2] + n1 * h[5] + n2 * h[8]);
    {
      float a0 = va[0] * h[0] + va[1] * h[3] + va[2] * h[6];
      float a1 = va[0] * h[1] + va[1] * h[4] + va[2] * h[7];
      float a2 = va[0] * h[2] + va[1] * h[5] + va[2] * h[8];
      float b0 = vb[0] * h[0] + vb[1] * h[3] + vb[2] * h[6];
      float b1 = vb[0] * h[1] + vb[1] * h[4] + vb[2] * h[7];
      float b2 = vb[0] * h[2] + vb[1] * h[5] + vb[2] * h[8];
      p[3] = fabsf(a1 * va[2] - a2 * va[1]) + fabsf(a2 * va[0] - a0 * va[2]) +
             fabsf(a0 * va[1] - a1 * va[0]) + fabsf(b1 * vb[2] - b2 * vb[1]) +
             fabsf(b2 * vb[0] - b0 * vb[2]) + fabsf(b0 * vb[1] - b1 * vb[0]);
    }
    PQ o2;
#pragma unroll
    for (int k = 0; k < KVAL; ++k) {
      float R[9];
#pragma unroll
      for (int q = 0; q < 9; ++q) R[q] = B[L_R + 36 * t + 9 * k + q];
#pragma unroll
      for (int j = 0; j < 3; ++j) {
        float pa = R[j] * va[0] + R[3 + j] * va[1] + R[6 + j] * va[2];
        float pb = R[j] * vb[0] + R[3 + j] * vb[1] + R[6 + j] * vb[2];
        o2.h[6 * k + j] = (_Float16)pa;
        o2.h[6 * k + 3 + j] = (_Float16)pb;
      }
    }
    pq0[i] = o2.u[0]; pq1[i] = o2.u[1]; pq2[i] = o2.u[2];
  }

  block_reduce<5>(p);
  if (t == 0) {
#pragma unroll
    for (int q = 0; q < 5; ++q) part1[q * nb1 + blockIdx.x] = p[q];
  }
}

// ---- S3: neighbor consistency gather ---------------------------------------
__global__ __launch_bounds__(BLOCK) void s3_kernel(
    const u4v* __restrict__ vavb, const u4v* __restrict__ pq0,
    const u4v* __restrict__ pq1, const u4v* __restrict__ pq2,
    const i4* __restrict__ nbr, float* __restrict__ part2, int N) {
  int n = blockIdx.x * BLOCK + threadIdx.x;
  float p[1] = {0.f};
  if (n < N) {
    i4 jj = nbr[n];
    int js[4] = {jj.x, jj.y, jj.z, jj.w};
    VV wn[4];
#pragma unroll
    for (int k = 0; k < KVAL; ++k) wn[k].u4 = vavb[js[k]];
    PQ o;
    o.u[0] = pq0[n]; o.u[1] = pq1[n]; o.u[2] = pq2[n];
    float nsum = 0.f;
#pragma unroll
    for (int k = 0; k < KVAL; ++k) {
      float pa0 = (float)o.h[6 * k],     pa1 = (float)o.h[6 * k + 1],
            pa2 = (float)o.h[6 * k + 2];
      float pb0 = (float)o.h[6 * k + 3], pb1 = (float)o.h[6 * k + 4],
            pb2 = (float)o.h[6 * k + 5];
      float aj0 = (float)wn[k].h[0], aj1 = (float)wn[k].h[1], aj2 = (float)wn[k].h[2];
      float bj0 = (float)wn[k].h[3], bj1 = (float)wn[k].h[4], bj2 = (float)wn[k].h[5];
      nsum += fabsf(pa0 * aj0 + pa1 * aj1 + pa2 * aj2) +
              fabsf(pa0 * bj0 + pa1 * bj1 + pa2 * bj2) +
              fabsf(pb0 * aj0 + pb1 * aj1 + pb2 * aj2) +
              fabsf(pb0 * bj0 + pb1 * bj1 + pb2 * bj2) - 2.0f;
    }
    p[0] = nsum;
  }
  block_reduce<1>(p);
  if (threadIdx.x == 0) part2[blockIdx.x] = p[0];
}

// ---- finalize ---------------------------------------------------------------
__global__ __launch_bounds__(BLOCK) void finalize_fast(
    const float* __restrict__ part1, int nb1, const float* __restrict__ part2,
    int nb2, float* __restrict__ out, int N, int M) {
  float s[6] = {0.f, 0.f, 0.f, 0.f, 0.f, 0.f};
  for (int b = threadIdx.x; b < nb1; b += BLOCK) {
#pragma unroll
    for (int q = 0; q < 5; ++q) s[q] += part1[q * nb1 + b];
  }
  for (int b = threadIdx.x; b < nb2; b += BLOCK) s[5] += part2[b];
  block_reduce<6>(s);
  if (threadIdx.x == 0) {
    float sdf = s[0] / (float)N;
    float eik = s[1] / (float)(N + M);
    float morse = 0.5f * s[2] / (3.0f * (float)N);
    float th = 0.5f * s[3] / (3.0f * (float)N);
    float inter = s[4] / (float)M;
    float nb = s[5] / ((float)N * (float)KVAL);
    float loss = 7000.0f * sdf + 600.0f * inter + 50.0f * eik + 3.0f * morse +
                 10.0f * th + 30.0f * nb;
    out[0] = loss; out[1] = sdf; out[2] = inter; out[3] = eik;
    out[4] = morse; out[5] = th; out[6] = nb;
  }
}

// ---------------- fallback path (atomics, no ws tables) ---------------------
__device__ __forceinline__ void crossfield(const float* __restrict__ u,
                                           const float* __restrict__ v,
                                           const float* __restrict__ theta,
                                           int n, float va[3], float vb[3]) {
  float s, c;
  __sincosf(theta[n], &s, &c);
  float ux = u[3 * n], uy = u[3 * n + 1], uz = u[3 * n + 2];
  float vx = v[3 * n], vy = v[3 * n + 1], vz = v[3 * n + 2];
  norm3(ux * c + vx * s, uy * c + vy * s, uz * c + vz * s, va[0], va[1], va[2]);
  norm3(vx * c - ux * s, vy * c - uy * s, vz * c - uz * s, vb[0], vb[1], vb[2]);
}

__global__ __launch_bounds__(BLOCK) void vertex_kernel(
    const float* __restrict__ mp, const float* __restrict__ grad,
    const float* __restrict__ H, const float* __restrict__ ngt,
    const float* __restrict__ theta, const float* __restrict__ u,
    const float* __restrict__ v, const float* __restrict__ rot,
    const int* __restrict__ nbr, float* __restrict__ acc, int N) {
  int n = blockIdx.x * blockDim.x + threadIdx.x;
  float p[5] = {0.f, 0.f, 0.f, 0.f, 0.f};
  if (n < N) {
    float hh[9];
#pragma unroll
    for (int i = 0; i < 9; ++i) hh[i] = H[9 * (size_t)n + i];
    p[0] = fabsf(mp[n]);
    float gx = grad[3 * n], gy = grad[3 * n + 1], gz = grad[3 * n + 2];
    p[1] = fabsf(sqrtf(gx * gx + gy * gy + gz * gz) - 1.0f);
    float n0 = ngt[3 * n], n1 = ngt[3 * n + 1], n2 = ngt[3 * n + 2];
    p[2] = fabsf(n0 * hh[0] + n1 * hh[3] + n2 * hh[6]) +
           fabsf(n0 * hh[1] + n1 * hh[4] + n2 * hh[7]) +
           fabsf(n0 * hh[2] + n1 * hh[5] + n2 * hh[8]);
    float va[3], vb[3];
    crossfield(u, v, theta, n, va, vb);
    {
      float a0 = va[0] * hh[0] + va[1] * hh[3] + va[2] * hh[6];
      float a1 = va[0] * hh[1] + va[1] * hh[4] + va[2] * hh[7];
      float a2 = va[0] * hh[2] + va[1] * hh[5] + va[2] * hh[8];
      float b0 = vb[0] * hh[0] + vb[1] * hh[3] + vb[2] * hh[6];
      float b1 = vb[0] * hh[1] + vb[1] * hh[4] + vb[2] * hh[7];
      float b2 = vb[0] * hh[2] + vb[1] * hh[5] + vb[2] * hh[8];
      p[3] = fabsf(a1 * va[2] - a2 * va[1]) + fabsf(a2 * va[0] - a0 * va[2]) +
             fabsf(a0 * va[1] - a1 * va[0]) + fabsf(b1 * vb[2] - b2 * vb[1]) +
             fabsf(b2 * vb[0] - b0 * vb[2]) + fabsf(b0 * vb[1] - b1 * vb[0]);
    }
    float nsum = 0.f;
    const float* R = rot + (size_t)n * (KVAL * 9);
#pragma unroll
    for (int k = 0; k < KVAL; ++k) {
      int j = nbr[KVAL * (size_t)n + k];
      float vaj[3], vbj[3];
      crossfield(u, v, theta, j, vaj, vbj);
      float r0 = R[9 * k + 0], r1 = R[9 * k + 1], r2 = R[9 * k + 2];
      float r3 = R[9 * k + 3], r4 = R[9 * k + 4], r5 = R[9 * k + 5];
      float r6 = R[9 * k + 6], r7 = R[9 * k + 7], r8 = R[9 * k + 8];
      float wa0 = r0 * vaj[0] + r1 * vaj[1] + r2 * vaj[2];
      float wa1 = r3 * vaj[0] + r4 * vaj[1] + r5 * vaj[2];
      float wa2 = r6 * vaj[0] + r7 * vaj[1] + r8 * vaj[2];
      float wb0 = r0 * vbj[0] + r1 * vbj[1] + r2 * vbj[2];
      float wb1 = r3 * vbj[0] + r4 * vbj[1] + r5 * vbj[2];
      float wb2 = r6 * vbj[0] + r7 * vbj[1] + r8 * vbj[2];
      nsum += fabsf(va[0] * wa0 + va[1] * wa1 + va[2] * wa2) +
              fabsf(va[0] * wb0 + va[1] * wb1 + va[2] * wb2) +
              fabsf(vb[0] * wa0 + vb[1] * wa1 + vb[2] * wa2) +
              fabsf(vb[0] * wb0 + vb[1] * wb1 + vb[2] * wb2) - 2.0f;
    }
    p[4] = nsum;
  }
  block_reduce<5>(p);
  if (threadIdx.x == 0) {
    atomicAdd(&acc[0], p[0]); atomicAdd(&acc[1], p[1]); atomicAdd(&acc[2], p[2]);
    atomicAdd(&acc[3], p[3]); atomicAdd(&acc[4], p[4]);
  }
}

__global__ __launch_bounds__(BLOCK) void point_kernel(
    const float* __restrict__ pred, const float* __restrict__ grad,
    float* __restrict__ acc, int M) {
  int i = blockIdx.x * blockDim.x + threadIdx.x;
  float p[2] = {0.f, 0.f};
  if (i < M) {
    p[0] = __expf(-100.0f * fabsf(pred[i]));
    float gx = grad[3 * i], gy = grad[3 * i + 1], gz = grad[3 * i + 2];
    p[1] = fabsf(sqrtf(gx * gx + gy * gy + gz * gz) - 1.0f);
  }
  block_reduce<2>(p);
  if (threadIdx.x == 0) {
    atomicAdd(&acc[5], p[0]); atomicAdd(&acc[1], p[1]);
  }
}

__global__ void finalize_acc(const float* __restrict__ acc, float* __restrict__ out,
                             int N, int M) {
  if (threadIdx.x == 0 && blockIdx.x == 0) {
    float sdf = acc[0] / (float)N;
    float eik = acc[1] / (float)(N + M);
    float morse = 0.5f * acc[2] / (3.0f * (float)N);
    float th = 0.5f * acc[3] / (3.0f * (float)N);
    float nb = acc[4] / ((float)N * (float)KVAL);
    float inter = acc[5] / (float)M;
    float loss = 7000.0f * sdf + 600.0f * inter + 50.0f * eik + 3.0f * morse +
                 10.0f * th + 30.0f * nb;
    out[0] = loss; out[1] = sdf; out[2] = inter; out[3] = eik;
    out[4] = morse; out[5] = th; out[6] = nb;
  }
}

extern "C" void kernel_launch(void* const* d_in, const int* in_sizes, int n_in,
                              void* d_out, int out_size, void* d_ws, size_t ws_size,
                              hipStream_t stream) {
  const float* mp    = (const float*)d_in[0];
  const float* npred = (const float*)d_in[1];
  const float* grad  = (const float*)d_in[2];
  const float* ngrad = (const float*)d_in[3];
  const float* H     = (const float*)d_in[4];
  const float* ngt   = (const float*)d_in[5];
  const float* theta = (const float*)d_in[6];
  const float* u     = (const float*)d_in[7];
  const float* v     = (const float*)d_in[8];
  const float* rot   = (const float*)d_in[9];
  const int*   nbr   = (const int*)d_in[10];
  float* out = (float*)d_out;

  int N = in_sizes[0];
  int M = in_sizes[1];
  int mx = (N > M) ? N : M;
  int nb1 = (mx + TILE - 1) / TILE;         // s1 blocks
  int nb2 = (N + BLOCK - 1) / BLOCK;        // s3 blocks

  size_t off_vavb = 256;
  size_t off_pq0 = off_vavb + (size_t)N * 16;
  size_t off_pq1 = off_pq0 + (size_t)N * 16;
  size_t off_pq2 = off_pq1 + (size_t)N * 16;
  size_t off_p1 = off_pq2 + (size_t)N * 16;
  size_t off_p2 = off_p1 + (size_t)5 * nb1 * 4;
  size_t need = off_p2 + (size_t)nb2 * 4;

  if (ws_size >= need) {
    u4v* vavb    = (u4v*)((char*)d_ws + off_vavb);
    u4v* pq0     = (u4v*)((char*)d_ws + off_pq0);
    u4v* pq1     = (u4v*)((char*)d_ws + off_pq1);
    u4v* pq2     = (u4v*)((char*)d_ws + off_pq2);
    float* part1 = (float*)((char*)d_ws + off_p1);
    float* part2 = (float*)((char*)d_ws + off_p2);
    s1_kernel<<<nb1, BLOCK, 0, stream>>>(
        theta, u, v, vavb, pq0, pq1, pq2, N, npred, ngrad, mp, grad, H, ngt,
        rot, part1, nb1, M);
    s3_kernel<<<nb2, BLOCK, 0, stream>>>(
        vavb, pq0, pq1, pq2, (const i4*)nbr, part2, N);
    finalize_fast<<<1, BLOCK, 0, stream>>>(part1, nb1, part2, nb2, out, N, M);
  } else {
    float* acc = (float*)d_ws;
    (void)hipMemsetAsync(acc, 0, 6 * sizeof(float), stream);
    vertex_kernel<<<(N + BLOCK - 1) / BLOCK, BLOCK, 0, stream>>>(
        mp, grad, H, ngt, theta, u, v, rot, nbr, acc, N);
    point_kernel<<<(M + BLOCK - 1) / BLOCK, BLOCK, 0, stream>>>(npred, ngrad, acc, M);
    finalize_acc<<<1, 64, 0, stream>>>(acc, out, N, M);
  }
}

// Round 11
// 64.151 us; speedup vs baseline: 1.0135x; 1.0135x over previous
//
#include <hip/hip_runtime.h>
#include <math.h>

static constexpr int BLOCK = 256;
static constexpr int WAVES = BLOCK / 64;
static constexpr int KVAL = 4;
static constexpr int TILE = 256;   // vertices per tile; 2 tiles per s1 block

typedef float f4 __attribute__((ext_vector_type(4)));
typedef int i4 __attribute__((ext_vector_type(4)));
typedef unsigned int u4v __attribute__((ext_vector_type(4)));
union VV { u4v u4; _Float16 h[8]; };
union PQ { u4v u[3]; _Float16 h[24]; };

__device__ __forceinline__ void gld_lds16(const void* g, void* l) {
  __builtin_amdgcn_global_load_lds(
      (const __attribute__((address_space(1))) void*)g,
      (__attribute__((address_space(3))) void*)l, 16, 0, 0);
}

__device__ __forceinline__ void norm3(float x, float y, float z,
                                      float& ox, float& oy, float& oz) {
  float inv = 1.0f / (sqrtf(x * x + y * y + z * z) + 1e-12f);
  ox = x * inv; oy = y * inv; oz = z * inv;
}

template <int NV>
__device__ __forceinline__ void block_reduce(float (&p)[NV]) {
#pragma unroll
  for (int off = 32; off > 0; off >>= 1)
#pragma unroll
    for (int q = 0; q < NV; ++q) p[q] += __shfl_down(p[q], off, 64);
  __shared__ float sm[WAVES][NV];
  int wave = threadIdx.x >> 6, lane = threadIdx.x & 63;
  if (lane == 0)
#pragma unroll
    for (int q = 0; q < NV; ++q) sm[wave][q] = p[q];
  __syncthreads();
  if (threadIdx.x == 0) {
#pragma unroll
    for (int q = 0; q < NV; ++q) {
      float t = 0.f;
#pragma unroll
      for (int w = 1; w < WAVES; ++w) t += sm[w][q];
      p[q] += t;
    }
  }
}

__device__ __forceinline__ void stage_f(float* __restrict__ dst,
                                        const float* __restrict__ src, int nf) {
  int t = threadIdx.x;
  int nf4 = nf >> 2;
  const f4* s4 = (const f4*)src;
  f4* d4 = (f4*)dst;
  for (int i = t; i < nf4; i += BLOCK) d4[i] = s4[i];
  int rem = nf & 3;
  if (t < rem) dst[nf4 * 4 + t] = src[nf4 * 4 + t];
}

// per-vertex math for one tile; rot row comes from LDS. p = {sdf,eik,morse,halign}
__device__ __forceinline__ void tile_compute(
    const float* __restrict__ Brot, int t, long i,
    float mpv, float thv, float gx, float gy, float gz,
    float n0, float n1, float n2,
    float ux, float uy, float uz, float vx, float vy, float vz,
    float h0, float h1, float h2, float h3, float h4, float h5,
    float h6, float h7, float h8,
    u4v* __restrict__ vavb, u4v* __restrict__ pq0, u4v* __restrict__ pq1,
    u4v* __restrict__ pq2, float (&p)[4]) {
  p[0] += fabsf(mpv);
  p[1] += fabsf(sqrtf(gx * gx + gy * gy + gz * gz) - 1.0f);
  p[2] += fabsf(n0 * h0 + n1 * h3 + n2 * h6) +
          fabsf(n0 * h1 + n1 * h4 + n2 * h7) +
          fabsf(n0 * h2 + n1 * h5 + n2 * h8);
  float s, c;
  __sincosf(thv, &s, &c);
  float va[3], vb[3];
  norm3(ux * c + vx * s, uy * c + vy * s, uz * c + vz * s, va[0], va[1], va[2]);
  norm3(vx * c - ux * s, vy * c - uy * s, vz * c - uz * s, vb[0], vb[1], vb[2]);
  {
    float a0 = va[0] * h0 + va[1] * h3 + va[2] * h6;
    float a1 = va[0] * h1 + va[1] * h4 + va[2] * h7;
    float a2 = va[0] * h2 + va[1] * h5 + va[2] * h8;
    float b0 = vb[0] * h0 + vb[1] * h3 + vb[2] * h6;
    float b1 = vb[0] * h1 + vb[1] * h4 + vb[2] * h7;
    float b2 = vb[0] * h2 + vb[1] * h5 + vb[2] * h8;
    p[3] += fabsf(a1 * va[2] - a2 * va[1]) + fabsf(a2 * va[0] - a0 * va[2]) +
            fabsf(a0 * va[1] - a1 * va[0]) + fabsf(b1 * vb[2] - b2 * vb[1]) +
            fabsf(b2 * vb[0] - b0 * vb[2]) + fabsf(b0 * vb[1] - b1 * vb[0]);
  }
  VV o;
  o.h[0] = (_Float16)va[0]; o.h[1] = (_Float16)va[1]; o.h[2] = (_Float16)va[2];
  o.h[3] = (_Float16)vb[0]; o.h[4] = (_Float16)vb[1]; o.h[5] = (_Float16)vb[2];
  o.h[6] = (_Float16)0.f;   o.h[7] = (_Float16)0.f;
  vavb[i] = o.u4;
  const float* R0 = Brot + 36 * t;
  PQ o2;
#pragma unroll
  for (int k = 0; k < KVAL; ++k) {
    float R[9];
#pragma unroll
    for (int q = 0; q < 9; ++q) R[q] = R0[9 * k + q];
#pragma unroll
    for (int j = 0; j < 3; ++j) {
      float pa = R[j] * va[0] + R[3 + j] * va[1] + R[6 + j] * va[2];
      float pb = R[j] * vb[0] + R[3 + j] * vb[1] + R[6 + j] * vb[2];
      o2.h[6 * k + j] = (_Float16)pa;
      o2.h[6 * k + 3 + j] = (_Float16)pb;
    }
  }
  pq0[i] = o2.u[0]; pq1[i] = o2.u[1]; pq2[i] = o2.u[2];
}

// ---- S1: vertex streaming terms; 2-tile pipelined rot DMA, counted vmcnt ---
__global__ __launch_bounds__(BLOCK) void s1_kernel(
    const float* __restrict__ theta, const float* __restrict__ u,
    const float* __restrict__ v, u4v* __restrict__ vavb,
    u4v* __restrict__ pq0, u4v* __restrict__ pq1, u4v* __restrict__ pq2, int N,
    const float* __restrict__ mp, const float* __restrict__ grad,
    const float* __restrict__ H, const float* __restrict__ ngt,
    const float* __restrict__ rot, float* __restrict__ part1, int nbb) {
  __shared__ float B[2][36 * TILE];
  int t = threadIdx.x;
  long b0 = (long)blockIdx.x * (2 * TILE);
  long b1 = b0 + TILE;
  int cnt0 = 0, cnt1 = 0;
  if (b0 < N) { long c = (long)N - b0; cnt0 = c > TILE ? TILE : (int)c; }
  if (b1 < N) { long c = (long)N - b1; cnt1 = c > TILE ? TILE : (int)c; }
  float p[4] = {0.f, 0.f, 0.f, 0.f};  // sdf, eik, morse, halign

  if (cnt0 == TILE && cnt1 == TILE) {
    long i0 = b0 + t, i1 = b1 + t;
    // scalar loads for both tiles (issued first; retire before the DMA waits)
    float mp0 = mp[i0], th0 = theta[i0];
    float g0x = grad[3 * i0], g0y = grad[3 * i0 + 1], g0z = grad[3 * i0 + 2];
    float n00 = ngt[3 * i0], n01 = ngt[3 * i0 + 1], n02 = ngt[3 * i0 + 2];
    float u0x = u[3 * i0], u0y = u[3 * i0 + 1], u0z = u[3 * i0 + 2];
    float v0x = v[3 * i0], v0y = v[3 * i0 + 1], v0z = v[3 * i0 + 2];
    float h0[9];
#pragma unroll
    for (int q = 0; q < 9; ++q) h0[q] = H[9 * i0 + q];
    float mp1 = mp[i1], th1 = theta[i1];
    float g1x = grad[3 * i1], g1y = grad[3 * i1 + 1], g1z = grad[3 * i1 + 2];
    float n10 = ngt[3 * i1], n11 = ngt[3 * i1 + 1], n12 = ngt[3 * i1 + 2];
    float u1x = u[3 * i1], u1y = u[3 * i1 + 1], u1z = u[3 * i1 + 2];
    float v1x = v[3 * i1], v1y = v[3 * i1 + 1], v1z = v[3 * i1 + 2];
    float h1[9];
#pragma unroll
    for (int q = 0; q < 9; ++q) h1[q] = H[9 * i1 + q];

    // rot DMA: 36 x 1KB chunks per tile, round-robin across 4 waves (9/wave)
    int wave = t >> 6, lane = t & 63;
    const char* r0 = (const char*)(rot + 36 * b0);
    const char* r1 = (const char*)(rot + 36 * b1);
#pragma unroll
    for (int c0 = 0; c0 < 9; ++c0) {
      int c = wave + 4 * c0;
      gld_lds16(r0 + c * 1024 + lane * 16, (char*)B[0] + c * 1024);
    }
#pragma unroll
    for (int c0 = 0; c0 < 9; ++c0) {
      int c = wave + 4 * c0;
      gld_lds16(r1 + c * 1024 + lane * 16, (char*)B[1] + c * 1024);
    }
    // wait: everything except tile1's 9 DMA chunks has landed
    asm volatile("s_waitcnt vmcnt(9)" ::: "memory");
    __builtin_amdgcn_s_barrier();
    tile_compute(B[0], t, i0, mp0, th0, g0x, g0y, g0z, n00, n01, n02,
                 u0x, u0y, u0z, v0x, v0y, v0z,
                 h0[0], h0[1], h0[2], h0[3], h0[4], h0[5], h0[6], h0[7], h0[8],
                 vavb, pq0, pq1, pq2, p);
    asm volatile("s_waitcnt vmcnt(0)" ::: "memory");
    __builtin_amdgcn_s_barrier();
    tile_compute(B[1], t, i1, mp1, th1, g1x, g1y, g1z, n10, n11, n12,
                 u1x, u1y, u1z, v1x, v1y, v1z,
                 h1[0], h1[1], h1[2], h1[3], h1[4], h1[5], h1[6], h1[7], h1[8],
                 vavb, pq0, pq1, pq2, p);
  } else {
    // tail path: plain staging + full barriers
    if (cnt0 > 0) stage_f(B[0], rot + 36 * b0, 36 * cnt0);
    if (cnt1 > 0) stage_f(B[1], rot + 36 * b1, 36 * cnt1);
    __syncthreads();
    if (t < cnt0) {
      long i = b0 + t;
      tile_compute(B[0], t, i, mp[i], theta[i],
                   grad[3 * i], grad[3 * i + 1], grad[3 * i + 2],
                   ngt[3 * i], ngt[3 * i + 1], ngt[3 * i + 2],
                   u[3 * i], u[3 * i + 1], u[3 * i + 2],
                   v[3 * i], v[3 * i + 1], v[3 * i + 2],
                   H[9 * i], H[9 * i + 1], H[9 * i + 2], H[9 * i + 3],
                   H[9 * i + 4], H[9 * i + 5], H[9 * i + 6], H[9 * i + 7],
                   H[9 * i + 8], vavb, pq0, pq1, pq2, p);
    }
    if (t < cnt1) {
      long i = b1 + t;
      tile_compute(B[1], t, i, mp[i], theta[i],
                   grad[3 * i], grad[3 * i + 1], grad[3 * i + 2],
                   ngt[3 * i], ngt[3 * i + 1], ngt[3 * i + 2],
                   u[3 * i], u[3 * i + 1], u[3 * i + 2],
                   v[3 * i], v[3 * i + 1], v[3 * i + 2],
                   H[9 * i], H[9 * i + 1], H[9 * i + 2], H[9 * i + 3],
                   H[9 * i + 4], H[9 * i + 5], H[9 * i + 6], H[9 * i + 7],
                   H[9 * i + 8], vavb, pq0, pq1, pq2, p);
    }
  }

  block_reduce<4>(p);
  if (t == 0) {
#pragma unroll
    for (int q = 0; q < 4; ++q) part1[q * nbb + blockIdx.x] = p[q];
  }
}

// ---- S3: neighbor consistency gather + point terms -------------------------
__global__ __launch_bounds__(BLOCK) void s3_kernel(
    const u4v* __restrict__ vavb, const u4v* __restrict__ pq0,
    const u4v* __restrict__ pq1, const u4v* __restrict__ pq2,
    const i4* __restrict__ nbr, const float* __restrict__ pred,
    const float* __restrict__ pgrad, float* __restrict__ part2,
    int N, int M, int nb2) {
  int n = blockIdx.x * BLOCK + threadIdx.x;
  float p[3] = {0.f, 0.f, 0.f};  // neigh, eik(point), inter
  if (n < M) {
    p[2] = __expf(-100.0f * fabsf(pred[n]));
    float gx = pgrad[3 * (long)n], gy = pgrad[3 * (long)n + 1],
          gz = pgrad[3 * (long)n + 2];
    p[1] = fabsf(sqrtf(gx * gx + gy * gy + gz * gz) - 1.0f);
  }
  if (n < N) {
    i4 jj = nbr[n];
    int js[4] = {jj.x, jj.y, jj.z, jj.w};
    VV wn[4];
#pragma unroll
    for (int k = 0; k < KVAL; ++k) wn[k].u4 = vavb[js[k]];
    PQ o;
    o.u[0] = pq0[n]; o.u[1] = pq1[n]; o.u[2] = pq2[n];
    float nsum = 0.f;
#pragma unroll
    for (int k = 0; k < KVAL; ++k) {
      float pa0 = (float)o.h[6 * k],     pa1 = (float)o.h[6 * k + 1],
            pa2 = (float)o.h[6 * k + 2];
      float pb0 = (float)o.h[6 * k + 3], pb1 = (float)o.h[6 * k + 4],
            pb2 = (float)o.h[6 * k + 5];
      float aj0 = (float)wn[k].h[0], aj1 = (float)wn[k].h[1], aj2 = (float)wn[k].h[2];
      float bj0 = (float)wn[k].h[3], bj1 = (float)wn[k].h[4], bj2 = (float)wn[k].h[5];
      nsum += fabsf(pa0 * aj0 + pa1 * aj1 + pa2 * aj2) +
              fabsf(pa0 * bj0 + pa1 * bj1 + pa2 * bj2) +
              fabsf(pb0 * aj0 + pb1 * aj1 + pb2 * aj2) +
              fabsf(pb0 * bj0 + pb1 * bj1 + pb2 * bj2) - 2.0f;
    }
    p[0] = nsum;
  }
  block_reduce<3>(p);
  if (threadIdx.x == 0) {
#pragma unroll
    for (int q = 0; q < 3; ++q) part2[q * nb2 + blockIdx.x] = p[q];
  }
}

// ---- finalize ---------------------------------------------------------------
__global__ __launch_bounds__(BLOCK) void finalize_fast(
    const float* __restrict__ part1, int nb1, const float* __restrict__ part2,
    int nb2, float* __restrict__ out, int N, int M) {
  float s[6] = {0.f, 0.f, 0.f, 0.f, 0.f, 0.f};
  // part1: sdf, eik(manifold), morse, halign
  for (int b = threadIdx.x; b < nb1; b += BLOCK) {
    s[0] += part1[0 * nb1 + b];
    s[1] += part1[1 * nb1 + b];
    s[2] += part1[2 * nb1 + b];
    s[3] += part1[3 * nb1 + b];
  }
  // part2: neigh, eik(point), inter
  for (int b = threadIdx.x; b < nb2; b += BLOCK) {
    s[5] += part2[0 * nb2 + b];
    s[1] += part2[1 * nb2 + b];
    s[4] += part2[2 * nb2 + b];
  }
  block_reduce<6>(s);
  if (threadIdx.x == 0) {
    float sdf = s[0] / (float)N;
    float eik = s[1] / (float)(N + M);
    float morse = 0.5f * s[2] / (3.0f * (float)N);
    float th = 0.5f * s[3] / (3.0f * (float)N);
    float inter = s[4] / (float)M;
    float nb = s[5] / ((float)N * (float)KVAL);
    float loss = 7000.0f * sdf + 600.0f * inter + 50.0f * eik + 3.0f * morse +
                 10.0f * th + 30.0f * nb;
    out[0] = loss; out[1] = sdf; out[2] = inter; out[3] = eik;
    out[4] = morse; out[5] = th; out[6] = nb;
  }
}

// ---------------- fallback path (atomics, no ws tables) ---------------------
__device__ __forceinline__ void crossfield(const float* __restrict__ u,
                                           const float* __restrict__ v,
                                           const float* __restrict__ theta,
                                           int n, float va[3], float vb[3]) {
  float s, c;
  __sincosf(theta[n], &s, &c);
  float ux = u[3 * n], uy = u[3 * n + 1], uz = u[3 * n + 2];
  float vx = v[3 * n], vy = v[3 * n + 1], vz = v[3 * n + 2];
  norm3(ux * c + vx * s, uy * c + vy * s, uz * c + vz * s, va[0], va[1], va[2]);
  norm3(vx * c - ux * s, vy * c - uy * s, vz * c - uz * s, vb[0], vb[1], vb[2]);
}

__global__ __launch_bounds__(BLOCK) void vertex_kernel(
    const float* __restrict__ mp, const float* __restrict__ grad,
    const float* __restrict__ H, const float* __restrict__ ngt,
    const float* __restrict__ theta, const float* __restrict__ u,
    const float* __restrict__ v, const float* __restrict__ rot,
    const int* __restrict__ nbr, float* __restrict__ acc, int N) {
  int n = blockIdx.x * blockDim.x + threadIdx.x;
  float p[5] = {0.f, 0.f, 0.f, 0.f, 0.f};
  if (n < N) {
    float hh[9];
#pragma unroll
    for (int i = 0; i < 9; ++i) hh[i] = H[9 * (size_t)n + i];
    p[0] = fabsf(mp[n]);
    float gx = grad[3 * n], gy = grad[3 * n + 1], gz = grad[3 * n + 2];
    p[1] = fabsf(sqrtf(gx * gx + gy * gy + gz * gz) - 1.0f);
    float n0 = ngt[3 * n], n1 = ngt[3 * n + 1], n2 = ngt[3 * n + 2];
    p[2] = fabsf(n0 * hh[0] + n1 * hh[3] + n2 * hh[6]) +
           fabsf(n0 * hh[1] + n1 * hh[4] + n2 * hh[7]) +
           fabsf(n0 * hh[2] + n1 * hh[5] + n2 * hh[8]);
    float va[3], vb[3];
    crossfield(u, v, theta, n, va, vb);
    {
      float a0 = va[0] * hh[0] + va[1] * hh[3] + va[2] * hh[6];
      float a1 = va[0] * hh[1] + va[1] * hh[4] + va[2] * hh[7];
      float a2 = va[0] * hh[2] + va[1] * hh[5] + va[2] * hh[8];
      float b0 = vb[0] * hh[0] + vb[1] * hh[3] + vb[2] * hh[6];
      float b1 = vb[0] * hh[1] + vb[1] * hh[4] + vb[2] * hh[7];
      float b2 = vb[0] * hh[2] + vb[1] * hh[5] + vb[2] * hh[8];
      p[3] = fabsf(a1 * va[2] - a2 * va[1]) + fabsf(a2 * va[0] - a0 * va[2]) +
             fabsf(a0 * va[1] - a1 * va[0]) + fabsf(b1 * vb[2] - b2 * vb[1]) +
             fabsf(b2 * vb[0] - b0 * vb[2]) + fabsf(b0 * vb[1] - b1 * vb[0]);
    }
    float nsum = 0.f;
    const float* R = rot + (size_t)n * (KVAL * 9);
#pragma unroll
    for (int k = 0; k < KVAL; ++k) {
      int j = nbr[KVAL * (size_t)n + k];
      float vaj[3], vbj[3];
      crossfield(u, v, theta, j, vaj, vbj);
      float r0 = R[9 * k + 0], r1 = R[9 * k + 1], r2 = R[9 * k + 2];
      float r3 = R[9 * k + 3], r4 = R[9 * k + 4], r5 = R[9 * k + 5];
      float r6 = R[9 * k + 6], r7 = R[9 * k + 7], r8 = R[9 * k + 8];
      float wa0 = r0 * vaj[0] + r1 * vaj[1] + r2 * vaj[2];
      float wa1 = r3 * vaj[0] + r4 * vaj[1] + r5 * vaj[2];
      float wa2 = r6 * vaj[0] + r7 * vaj[1] + r8 * vaj[2];
      float wb0 = r0 * vbj[0] + r1 * vbj[1] + r2 * vbj[2];
      float wb1 = r3 * vbj[0] + r4 * vbj[1] + r5 * vbj[2];
      float wb2 = r6 * vbj[0] + r7 * vbj[1] + r8 * vbj[2];
      nsum += fabsf(va[0] * wa0 + va[1] * wa1 + va[2] * wa2) +
              fabsf(va[0] * wb0 + va[1] * wb1 + va[2] * wb2) +
              fabsf(vb[0] * wa0 + vb[1] * wa1 + vb[2] * wa2) +
              fabsf(vb[0] * wb0 + vb[1] * wb1 + vb[2] * wb2) - 2.0f;
    }
    p[4] = nsum;
  }
  block_reduce<5>(p);
  if (threadIdx.x == 0) {
    atomicAdd(&acc[0], p[0]); atomicAdd(&acc[1], p[1]); atomicAdd(&acc[2], p[2]);
    atomicAdd(&acc[3], p[3]); atomicAdd(&acc[4], p[4]);
  }
}

__global__ __launch_bounds__(BLOCK) void point_kernel(
    const float* __restrict__ pred, const float* __restrict__ grad,
    float* __restrict__ acc, int M) {
  int i = blockIdx.x * blockDim.x + threadIdx.x;
  float p[2] = {0.f, 0.f};
  if (i < M) {
    p[0] = __expf(-100.0f * fabsf(pred[i]));
    float gx = grad[3 * i], gy = grad[3 * i + 1], gz = grad[3 * i + 2];
    p[1] = fabsf(sqrtf(gx * gx + gy * gy + gz * gz) - 1.0f);
  }
  block_reduce<2>(p);
  if (threadIdx.x == 0) {
    atomicAdd(&acc[5], p[0]); atomicAdd(&acc[1], p[1]);
  }
}

__global__ void finalize_acc(const float* __restrict__ acc, float* __restrict__ out,
                             int N, int M) {
  if (threadIdx.x == 0 && blockIdx.x == 0) {
    float sdf = acc[0] / (float)N;
    float eik = acc[1] / (float)(N + M);
    float morse = 0.5f * acc[2] / (3.0f * (float)N);
    float th = 0.5f * acc[3] / (3.0f * (float)N);
    float nb = acc[4] / ((float)N * (float)KVAL);
    float inter = acc[5] / (float)M;
    float loss = 7000.0f * sdf + 600.0f * inter + 50.0f * eik + 3.0f * morse +
                 10.0f * th + 30.0f * nb;
    out[0] = loss; out[1] = sdf; out[2] = inter; out[3] = eik;
    out[4] = morse; out[5] = th; out[6] = nb;
  }
}

extern "C" void kernel_launch(void* const* d_in, const int* in_sizes, int n_in,
                              void* d_out, int out_size, void* d_ws, size_t ws_size,
                              hipStream_t stream) {
  const float* mp    = (const float*)d_in[0];
  const float* npred = (const float*)d_in[1];
  const float* grad  = (const float*)d_in[2];
  const float* ngrad = (const float*)d_in[3];
  const float* H     = (const float*)d_in[4];
  const float* ngt   = (const float*)d_in[5];
  const float* theta = (const float*)d_in[6];
  const float* u     = (const float*)d_in[7];
  const float* v     = (const float*)d_in[8];
  const float* rot   = (const float*)d_in[9];
  const int*   nbr   = (const int*)d_in[10];
  float* out = (float*)d_out;

  int N = in_sizes[0];
  int M = in_sizes[1];
  int mx = (N > M) ? N : M;
  int ntiles = (N + TILE - 1) / TILE;
  int nb1 = (ntiles + 1) / 2;               // s1 blocks (2 tiles each)
  int nb2 = (mx + BLOCK - 1) / BLOCK;       // s3 blocks

  size_t off_vavb = 256;
  size_t off_pq0 = off_vavb + (size_t)N * 16;
  size_t off_pq1 = off_pq0 + (size_t)N * 16;
  size_t off_pq2 = off_pq1 + (size_t)N * 16;
  size_t off_p1 = off_pq2 + (size_t)N * 16;
  size_t off_p2 = off_p1 + (size_t)4 * nb1 * 4;
  size_t need = off_p2 + (size_t)3 * nb2 * 4;

  if (ws_size >= need) {
    u4v* vavb    = (u4v*)((char*)d_ws + off_vavb);
    u4v* pq0     = (u4v*)((char*)d_ws + off_pq0);
    u4v* pq1     = (u4v*)((char*)d_ws + off_pq1);
    u4v* pq2     = (u4v*)((char*)d_ws + off_pq2);
    float* part1 = (float*)((char*)d_ws + off_p1);
    float* part2 = (float*)((char*)d_ws + off_p2);
    s1_kernel<<<nb1, BLOCK, 0, stream>>>(
        theta, u, v, vavb, pq0, pq1, pq2, N, mp, grad, H, ngt, rot, part1, nb1);
    s3_kernel<<<nb2, BLOCK, 0, stream>>>(
        vavb, pq0, pq1, pq2, (const i4*)nbr, npred, ngrad, part2, N, M, nb2);
    finalize_fast<<<1, BLOCK, 0, stream>>>(part1, nb1, part2, nb2, out, N, M);
  } else {
    float* acc = (float*)d_ws;
    (void)hipMemsetAsync(acc, 0, 6 * sizeof(float), stream);
    vertex_kernel<<<(N + BLOCK - 1) / BLOCK, BLOCK, 0, stream>>>(
        mp, grad, H, ngt, theta, u, v, rot, nbr, acc, N);
    point_kernel<<<(M + BLOCK - 1) / BLOCK, BLOCK, 0, stream>>>(npred, ngrad, acc, M);
    finalize_acc<<<1, 64, 0, stream>>>(acc, out, N, M);
  }
}

// Round 12
// 63.698 us; speedup vs baseline: 1.0207x; 1.0071x over previous
//
#include <hip/hip_runtime.h>
#include <math.h>

static constexpr int BLOCK = 256;
static constexpr int WAVES = BLOCK / 64;
static constexpr int KVAL = 4;
static constexpr int TILE = 256;  // vertices per s1 block

typedef float f4 __attribute__((ext_vector_type(4)));
typedef int i4 __attribute__((ext_vector_type(4)));
typedef unsigned int u4v __attribute__((ext_vector_type(4)));
union VV { u4v u4; _Float16 h[8]; };
union PQ { u4v u[3]; _Float16 h[24]; };

__device__ __forceinline__ void norm3(float x, float y, float z,
                                      float& ox, float& oy, float& oz) {
  float inv = 1.0f / (sqrtf(x * x + y * y + z * z) + 1e-12f);
  ox = x * inv; oy = y * inv; oz = z * inv;
}

template <int NV>
__device__ __forceinline__ void block_reduce(float (&p)[NV]) {
#pragma unroll
  for (int off = 32; off > 0; off >>= 1)
#pragma unroll
    for (int q = 0; q < NV; ++q) p[q] += __shfl_down(p[q], off, 64);
  __shared__ float sm[WAVES][NV];
  int wave = threadIdx.x >> 6, lane = threadIdx.x & 63;
  if (lane == 0)
#pragma unroll
    for (int q = 0; q < NV; ++q) sm[wave][q] = p[q];
  __syncthreads();
  if (threadIdx.x == 0) {
#pragma unroll
    for (int q = 0; q < NV; ++q) {
      float t = 0.f;
#pragma unroll
      for (int w = 1; w < WAVES; ++w) t += sm[w][q];
      p[q] += t;
    }
  }
}

__device__ __forceinline__ void stage_f(float* __restrict__ dst,
                                        const float* __restrict__ src, int nf) {
  int t = threadIdx.x;
  int nf4 = nf >> 2;
  const f4* s4 = (const f4*)src;
  f4* d4 = (f4*)dst;
  for (int i = t; i < nf4; i += BLOCK) d4[i] = s4[i];
  int rem = nf & 3;
  if (t < rem) dst[nf4 * 4 + t] = src[nf4 * 4 + t];
}

// ---- S1: all streaming terms; phased LDS staging, 18.4 KB LDS, 8 blk/CU ----
__global__ __launch_bounds__(BLOCK) void s1_kernel(
    const float* __restrict__ theta, const float* __restrict__ u,
    const float* __restrict__ v, u4v* __restrict__ vavb,
    u4v* __restrict__ pq0, u4v* __restrict__ pq1, u4v* __restrict__ pq2, int N,
    const float* __restrict__ pred, const float* __restrict__ pgrad,
    const float* __restrict__ mp, const float* __restrict__ grad,
    const float* __restrict__ H, const float* __restrict__ ngt,
    const float* __restrict__ rot,
    float* __restrict__ part1, int nb1, int M) {
  __shared__ float B[4608];  // 18.4 KB, reused across phases
  int t = threadIdx.x;
  long base = (long)blockIdx.x * TILE;
  float p[5] = {0.f, 0.f, 0.f, 0.f, 0.f};  // sdf, eik, morse, halign, inter

  int cntM = 0, cntN = 0;
  if (base < M) { long c = (long)M - base; cntM = c > TILE ? TILE : (int)c; }
  if (base < N) { long c = (long)N - base; cntN = c > TILE ? TILE : (int)c; }

  // stride-1 streams -> registers (coalesced)
  float prv = 0.f, mpv = 0.f, thv = 0.f;
  if (t < cntM) prv = pred[base + t];
  if (t < cntN) { mpv = mp[base + t]; thv = theta[base + t]; }

  // ---- phase A: pgrad | grad | ngt
  if (cntM > 0) stage_f(B, pgrad + 3 * base, 3 * cntM);
  if (cntN > 0) {
    stage_f(B + 768, grad + 3 * base, 3 * cntN);
    stage_f(B + 1536, ngt + 3 * base, 3 * cntN);
  }
  __syncthreads();
  float ng0 = 0.f, ng1 = 0.f, ng2 = 0.f;
  if (t < cntM) {
    float gx = B[3 * t], gy = B[3 * t + 1], gz = B[3 * t + 2];
    p[1] += fabsf(sqrtf(gx * gx + gy * gy + gz * gz) - 1.0f);
    p[4] += __expf(-100.0f * fabsf(prv));
  }
  if (t < cntN) {
    float gx = B[768 + 3 * t], gy = B[768 + 3 * t + 1], gz = B[768 + 3 * t + 2];
    p[1] += fabsf(sqrtf(gx * gx + gy * gy + gz * gz) - 1.0f);
    p[0] = fabsf(mpv);
    ng0 = B[1536 + 3 * t]; ng1 = B[1536 + 3 * t + 1]; ng2 = B[1536 + 3 * t + 2];
  }
  __syncthreads();

  // ---- phase B: u | v -> crossfield, write vavb
  if (cntN > 0) {
    stage_f(B, u + 3 * base, 3 * cntN);
    stage_f(B + 768, v + 3 * base, 3 * cntN);
  }
  __syncthreads();
  float va[3] = {0.f, 0.f, 0.f}, vb[3] = {0.f, 0.f, 0.f};
  if (t < cntN) {
    float s, c;
    __sincosf(thv, &s, &c);
    float ux = B[3 * t], uy = B[3 * t + 1], uz = B[3 * t + 2];
    float vx = B[768 + 3 * t], vy = B[768 + 3 * t + 1], vz = B[768 + 3 * t + 2];
    norm3(ux * c + vx * s, uy * c + vy * s, uz * c + vz * s, va[0], va[1], va[2]);
    norm3(vx * c - ux * s, vy * c - uy * s, vz * c - uz * s, vb[0], vb[1], vb[2]);
    VV o;
    o.h[0] = (_Float16)va[0]; o.h[1] = (_Float16)va[1]; o.h[2] = (_Float16)va[2];
    o.h[3] = (_Float16)vb[0]; o.h[4] = (_Float16)vb[1]; o.h[5] = (_Float16)vb[2];
    o.h[6] = (_Float16)0.f;   o.h[7] = (_Float16)0.f;
    vavb[base + t] = o.u4;
  }
  __syncthreads();

  // ---- phase C: H -> morse + hessian alignment
  if (cntN > 0) stage_f(B, H + 9 * base, 9 * cntN);
  __syncthreads();
  if (t < cntN) {
    float h[9];
#pragma unroll
    for (int q = 0; q < 9; ++q) h[q] = B[9 * t + q];
    p[2] = fabsf(ng0 * h[0] + ng1 * h[3] + ng2 * h[6]) +
           fabsf(ng0 * h[1] + ng1 * h[4] + ng2 * h[7]) +
           fabsf(ng0 * h[2] + ng1 * h[5] + ng2 * h[8]);
    float a0 = va[0] * h[0] + va[1] * h[3] + va[2] * h[6];
    float a1 = va[0] * h[1] + va[1] * h[4] + va[2] * h[7];
    float a2 = va[0] * h[2] + va[1] * h[5] + va[2] * h[8];
    float b0 = vb[0] * h[0] + vb[1] * h[3] + vb[2] * h[6];
    float b1 = vb[0] * h[1] + vb[1] * h[4] + vb[2] * h[7];
    float b2 = vb[0] * h[2] + vb[1] * h[5] + vb[2] * h[8];
    p[3] = fabsf(a1 * va[2] - a2 * va[1]) + fabsf(a2 * va[0] - a0 * va[2]) +
           fabsf(a0 * va[1] - a1 * va[0]) + fabsf(b1 * vb[2] - b2 * vb[1]) +
           fabsf(b2 * vb[0] - b0 * vb[2]) + fabsf(b0 * vb[1] - b1 * vb[0]);
  }
  __syncthreads();

  // ---- phase D: rot in 2 sub-tiles of 128 -> pq = R^T va | R^T vb
#pragma unroll
  for (int sp = 0; sp < 2; ++sp) {
    int cs = cntN - 128 * sp;
    if (cs < 0) cs = 0;
    if (cs > 128) cs = 128;
    if (cs > 0) stage_f(B, rot + 36 * (base + 128 * sp), 36 * cs);
    __syncthreads();
    int lt = t - 128 * sp;
    if (lt >= 0 && lt < cs) {
      long i = base + t;
      const float* R0 = B + 36 * lt;
      PQ o2;
#pragma unroll
      for (int k = 0; k < KVAL; ++k) {
        float R[9];
#pragma unroll
        for (int q = 0; q < 9; ++q) R[q] = R0[9 * k + q];
#pragma unroll
        for (int j = 0; j < 3; ++j) {
          float pa = R[j] * va[0] + R[3 + j] * va[1] + R[6 + j] * va[2];
          float pb = R[j] * vb[0] + R[3 + j] * vb[1] + R[6 + j] * vb[2];
          o2.h[6 * k + j] = (_Float16)pa;
          o2.h[6 * k + 3 + j] = (_Float16)pb;
        }
      }
      pq0[i] = o2.u[0]; pq1[i] = o2.u[1]; pq2[i] = o2.u[2];
    }
    __syncthreads();
  }

  block_reduce<5>(p);
  if (t == 0) {
#pragma unroll
    for (int q = 0; q < 5; ++q) part1[q * nb1 + blockIdx.x] = p[q];
  }
}

// ---- S3: neighbor consistency gather ---------------------------------------
__global__ __launch_bounds__(BLOCK) void s3_kernel(
    const u4v* __restrict__ vavb, const u4v* __restrict__ pq0,
    const u4v* __restrict__ pq1, const u4v* __restrict__ pq2,
    const i4* __restrict__ nbr, float* __restrict__ part2, int N) {
  int n = blockIdx.x * BLOCK + threadIdx.x;
  float p[1] = {0.f};
  if (n < N) {
    i4 jj = nbr[n];
    int js[4] = {jj.x, jj.y, jj.z, jj.w};
    VV wn[4];
#pragma unroll
    for (int k = 0; k < KVAL; ++k) wn[k].u4 = vavb[js[k]];
    PQ o;
    o.u[0] = pq0[n]; o.u[1] = pq1[n]; o.u[2] = pq2[n];
    float nsum = 0.f;
#pragma unroll
    for (int k = 0; k < KVAL; ++k) {
      float pa0 = (float)o.h[6 * k],     pa1 = (float)o.h[6 * k + 1],
            pa2 = (float)o.h[6 * k + 2];
      float pb0 = (float)o.h[6 * k + 3], pb1 = (float)o.h[6 * k + 4],
            pb2 = (float)o.h[6 * k + 5];
      float aj0 = (float)wn[k].h[0], aj1 = (float)wn[k].h[1], aj2 = (float)wn[k].h[2];
      float bj0 = (float)wn[k].h[3], bj1 = (float)wn[k].h[4], bj2 = (float)wn[k].h[5];
      nsum += fabsf(pa0 * aj0 + pa1 * aj1 + pa2 * aj2) +
              fabsf(pa0 * bj0 + pa1 * bj1 + pa2 * bj2) +
              fabsf(pb0 * aj0 + pb1 * aj1 + pb2 * aj2) +
              fabsf(pb0 * bj0 + pb1 * bj1 + pb2 * bj2) - 2.0f;
    }
    p[0] = nsum;
  }
  block_reduce<1>(p);
  if (threadIdx.x == 0) part2[blockIdx.x] = p[0];
}

// ---- finalize ---------------------------------------------------------------
__global__ __launch_bounds__(BLOCK) void finalize_fast(
    const float* __restrict__ part1, int nb1, const float* __restrict__ part2,
    int nb2, float* __restrict__ out, int N, int M) {
  float s[6] = {0.f, 0.f, 0.f, 0.f, 0.f, 0.f};
  for (int b = threadIdx.x; b < nb1; b += BLOCK) {
#pragma unroll
    for (int q = 0; q < 5; ++q) s[q] += part1[q * nb1 + b];
  }
  for (int b = threadIdx.x; b < nb2; b += BLOCK) s[5] += part2[b];
  block_reduce<6>(s);
  if (threadIdx.x == 0) {
    float sdf = s[0] / (float)N;
    float eik = s[1] / (float)(N + M);
    float morse = 0.5f * s[2] / (3.0f * (float)N);
    float th = 0.5f * s[3] / (3.0f * (float)N);
    float inter = s[4] / (float)M;
    float nb = s[5] / ((float)N * (float)KVAL);
    float loss = 7000.0f * sdf + 600.0f * inter + 50.0f * eik + 3.0f * morse +
                 10.0f * th + 30.0f * nb;
    out[0] = loss; out[1] = sdf; out[2] = inter; out[3] = eik;
    out[4] = morse; out[5] = th; out[6] = nb;
  }
}

// ---------------- fallback path (atomics, no ws tables) ---------------------
__device__ __forceinline__ void crossfield(const float* __restrict__ u,
                                           const float* __restrict__ v,
                                           const float* __restrict__ theta,
                                           int n, float va[3], float vb[3]) {
  float s, c;
  __sincosf(theta[n], &s, &c);
  float ux = u[3 * n], uy = u[3 * n + 1], uz = u[3 * n + 2];
  float vx = v[3 * n], vy = v[3 * n + 1], vz = v[3 * n + 2];
  norm3(ux * c + vx * s, uy * c + vy * s, uz * c + vz * s, va[0], va[1], va[2]);
  norm3(vx * c - ux * s, vy * c - uy * s, vz * c - uz * s, vb[0], vb[1], vb[2]);
}

__global__ __launch_bounds__(BLOCK) void vertex_kernel(
    const float* __restrict__ mp, const float* __restrict__ grad,
    const float* __restrict__ H, const float* __restrict__ ngt,
    const float* __restrict__ theta, const float* __restrict__ u,
    const float* __restrict__ v, const float* __restrict__ rot,
    const int* __restrict__ nbr, float* __restrict__ acc, int N) {
  int n = blockIdx.x * blockDim.x + threadIdx.x;
  float p[5] = {0.f, 0.f, 0.f, 0.f, 0.f};
  if (n < N) {
    float hh[9];
#pragma unroll
    for (int i = 0; i < 9; ++i) hh[i] = H[9 * (size_t)n + i];
    p[0] = fabsf(mp[n]);
    float gx = grad[3 * n], gy = grad[3 * n + 1], gz = grad[3 * n + 2];
    p[1] = fabsf(sqrtf(gx * gx + gy * gy + gz * gz) - 1.0f);
    float n0 = ngt[3 * n], n1 = ngt[3 * n + 1], n2 = ngt[3 * n + 2];
    p[2] = fabsf(n0 * hh[0] + n1 * hh[3] + n2 * hh[6]) +
           fabsf(n0 * hh[1] + n1 * hh[4] + n2 * hh[7]) +
           fabsf(n0 * hh[2] + n1 * hh[5] + n2 * hh[8]);
    float va[3], vb[3];
    crossfield(u, v, theta, n, va, vb);
    {
      float a0 = va[0] * hh[0] + va[1] * hh[3] + va[2] * hh[6];
      float a1 = va[0] * hh[1] + va[1] * hh[4] + va[2] * hh[7];
      float a2 = va[0] * hh[2] + va[1] * hh[5] + va[2] * hh[8];
      float b0 = vb[0] * hh[0] + vb[1] * hh[3] + vb[2] * hh[6];
      float b1 = vb[0] * hh[1] + vb[1] * hh[4] + vb[2] * hh[7];
      float b2 = vb[0] * hh[2] + vb[1] * hh[5] + vb[2] * hh[8];
      p[3] = fabsf(a1 * va[2] - a2 * va[1]) + fabsf(a2 * va[0] - a0 * va[2]) +
             fabsf(a0 * va[1] - a1 * va[0]) + fabsf(b1 * vb[2] - b2 * vb[1]) +
             fabsf(b2 * vb[0] - b0 * vb[2]) + fabsf(b0 * vb[1] - b1 * vb[0]);
    }
    float nsum = 0.f;
    const float* R = rot + (size_t)n * (KVAL * 9);
#pragma unroll
    for (int k = 0; k < KVAL; ++k) {
      int j = nbr[KVAL * (size_t)n + k];
      float vaj[3], vbj[3];
      crossfield(u, v, theta, j, vaj, vbj);
      float r0 = R[9 * k + 0], r1 = R[9 * k + 1], r2 = R[9 * k + 2];
      float r3 = R[9 * k + 3], r4 = R[9 * k + 4], r5 = R[9 * k + 5];
      float r6 = R[9 * k + 6], r7 = R[9 * k + 7], r8 = R[9 * k + 8];
      float wa0 = r0 * vaj[0] + r1 * vaj[1] + r2 * vaj[2];
      float wa1 = r3 * vaj[0] + r4 * vaj[1] + r5 * vaj[2];
      float wa2 = r6 * vaj[0] + r7 * vaj[1] + r8 * vaj[2];
      float wb0 = r0 * vbj[0] + r1 * vbj[1] + r2 * vbj[2];
      float wb1 = r3 * vbj[0] + r4 * vbj[1] + r5 * vbj[2];
      float wb2 = r6 * vbj[0] + r7 * vbj[1] + r8 * vbj[2];
      nsum += fabsf(va[0] * wa0 + va[1] * wa1 + va[2] * wa2) +
              fabsf(va[0] * wb0 + va[1] * wb1 + va[2] * wb2) +
              fabsf(vb[0] * wa0 + vb[1] * wa1 + vb[2] * wa2) +
              fabsf(vb[0] * wb0 + vb[1] * wb1 + vb[2] * wb2) - 2.0f;
    }
    p[4] = nsum;
  }
  block_reduce<5>(p);
  if (threadIdx.x == 0) {
    atomicAdd(&acc[0], p[0]); atomicAdd(&acc[1], p[1]); atomicAdd(&acc[2], p[2]);
    atomicAdd(&acc[3], p[3]); atomicAdd(&acc[4], p[4]);
  }
}

__global__ __launch_bounds__(BLOCK) void point_kernel(
    const float* __restrict__ pred, const float* __restrict__ grad,
    float* __restrict__ acc, int M) {
  int i = blockIdx.x * blockDim.x + threadIdx.x;
  float p[2] = {0.f, 0.f};
  if (i < M) {
    p[0] = __expf(-100.0f * fabsf(pred[i]));
    float gx = grad[3 * i], gy = grad[3 * i + 1], gz = grad[3 * i + 2];
    p[1] = fabsf(sqrtf(gx * gx + gy * gy + gz * gz) - 1.0f);
  }
  block_reduce<2>(p);
  if (threadIdx.x == 0) {
    atomicAdd(&acc[5], p[0]); atomicAdd(&acc[1], p[1]);
  }
}

__global__ void finalize_acc(const float* __restrict__ acc, float* __restrict__ out,
                             int N, int M) {
  if (threadIdx.x == 0 && blockIdx.x == 0) {
    float sdf = acc[0] / (float)N;
    float eik = acc[1] / (float)(N + M);
    float morse = 0.5f * acc[2] / (3.0f * (float)N);
    float th = 0.5f * acc[3] / (3.0f * (float)N);
    float nb = acc[4] / ((float)N * (float)KVAL);
    float inter = acc[5] / (float)M;
    float loss = 7000.0f * sdf + 600.0f * inter + 50.0f * eik + 3.0f * morse +
                 10.0f * th + 30.0f * nb;
    out[0] = loss; out[1] = sdf; out[2] = inter; out[3] = eik;
    out[4] = morse; out[5] = th; out[6] = nb;
  }
}

extern "C" void kernel_launch(void* const* d_in, const int* in_sizes, int n_in,
                              void* d_out, int out_size, void* d_ws, size_t ws_size,
                              hipStream_t stream) {
  const float* mp    = (const float*)d_in[0];
  const float* npred = (const float*)d_in[1];
  const float* grad  = (const float*)d_in[2];
  const float* ngrad = (const float*)d_in[3];
  const float* H     = (const float*)d_in[4];
  const float* ngt   = (const float*)d_in[5];
  const float* theta = (const float*)d_in[6];
  const float* u     = (const float*)d_in[7];
  const float* v     = (const float*)d_in[8];
  const float* rot   = (const float*)d_in[9];
  const int*   nbr   = (const int*)d_in[10];
  float* out = (float*)d_out;

  int N = in_sizes[0];
  int M = in_sizes[1];
  int mx = (N > M) ? N : M;
  int nb1 = (mx + TILE - 1) / TILE;         // s1 blocks
  int nb2 = (N + BLOCK - 1) / BLOCK;        // s3 blocks

  size_t off_vavb = 256;
  size_t off_pq0 = off_vavb + (size_t)N * 16;
  size_t off_pq1 = off_pq0 + (size_t)N * 16;
  size_t off_pq2 = off_pq1 + (size_t)N * 16;
  size_t off_p1 = off_pq2 + (size_t)N * 16;
  size_t off_p2 = off_p1 + (size_t)5 * nb1 * 4;
  size_t need = off_p2 + (size_t)nb2 * 4;

  if (ws_size >= need) {
    u4v* vavb    = (u4v*)((char*)d_ws + off_vavb);
    u4v* pq0     = (u4v*)((char*)d_ws + off_pq0);
    u4v* pq1     = (u4v*)((char*)d_ws + off_pq1);
    u4v* pq2     = (u4v*)((char*)d_ws + off_pq2);
    float* part1 = (float*)((char*)d_ws + off_p1);
    float* part2 = (float*)((char*)d_ws + off_p2);
    s1_kernel<<<nb1, BLOCK, 0, stream>>>(
        theta, u, v, vavb, pq0, pq1, pq2, N, npred, ngrad, mp, grad, H, ngt,
        rot, part1, nb1, M);
    s3_kernel<<<nb2, BLOCK, 0, stream>>>(
        vavb, pq0, pq1, pq2, (const i4*)nbr, part2, N);
    finalize_fast<<<1, BLOCK, 0, stream>>>(part1, nb1, part2, nb2, out, N, M);
  } else {
    float* acc = (float*)d_ws;
    (void)hipMemsetAsync(acc, 0, 6 * sizeof(float), stream);
    vertex_kernel<<<(N + BLOCK - 1) / BLOCK, BLOCK, 0, stream>>>(
        mp, grad, H, ngt, theta, u, v, rot, nbr, acc, N);
    point_kernel<<<(M + BLOCK - 1) / BLOCK, BLOCK, 0, stream>>>(npred, ngrad, acc, M);
    finalize_acc<<<1, 64, 0, stream>>>(acc, out, N, M);
  }
}

// Round 13
// 59.841 us; speedup vs baseline: 1.0864x; 1.0644x over previous
//
#include <hip/hip_runtime.h>
#include <math.h>

static constexpr int BLOCK = 256;
static constexpr int WAVES = BLOCK / 64;
static constexpr int KVAL = 4;
static constexpr int TILE = 256;

typedef float f4 __attribute__((ext_vector_type(4)));
typedef int i4 __attribute__((ext_vector_type(4)));
typedef unsigned int u4v __attribute__((ext_vector_type(4)));
union VV { u4v u4; _Float16 h[8]; };

__device__ __forceinline__ void nts4(u4v* p, u4v v) {
  __builtin_nontemporal_store(v, p);
}

__device__ __forceinline__ void norm3(float x, float y, float z,
                                      float& ox, float& oy, float& oz) {
  float inv = 1.0f / (sqrtf(x * x + y * y + z * z) + 1e-12f);
  ox = x * inv; oy = y * inv; oz = z * inv;
}

template <int NV>
__device__ __forceinline__ void block_reduce(float (&p)[NV]) {
#pragma unroll
  for (int off = 32; off > 0; off >>= 1)
#pragma unroll
    for (int q = 0; q < NV; ++q) p[q] += __shfl_down(p[q], off, 64);
  __shared__ float sm[WAVES][NV];
  int wave = threadIdx.x >> 6, lane = threadIdx.x & 63;
  if (lane == 0)
#pragma unroll
    for (int q = 0; q < NV; ++q) sm[wave][q] = p[q];
  __syncthreads();
  if (threadIdx.x == 0) {
#pragma unroll
    for (int q = 0; q < NV; ++q) {
      float t = 0.f;
#pragma unroll
      for (int w = 1; w < WAVES; ++w) t += sm[w][q];
      p[q] += t;
    }
  }
}

__device__ __forceinline__ void stage_f(float* __restrict__ dst,
                                        const float* __restrict__ src, int nf) {
  int t = threadIdx.x;
  int nf4 = nf >> 2;
  const f4* s4 = (const f4*)src;
  f4* d4 = (f4*)dst;
  for (int i = t; i < nf4; i += BLOCK) d4[i] = s4[i];
  int rem = nf & 3;
  if (t < rem) dst[nf4 * 4 + t] = src[nf4 * 4 + t];
}

// ---- S1: streaming terms (no rot, no pq); 9.2 KB LDS, phased ---------------
__global__ __launch_bounds__(BLOCK) void s1_kernel(
    const float* __restrict__ theta, const float* __restrict__ u,
    const float* __restrict__ v, u4v* __restrict__ vavb, int N,
    const float* __restrict__ pred, const float* __restrict__ pgrad,
    const float* __restrict__ mp, const float* __restrict__ grad,
    const float* __restrict__ H, const float* __restrict__ ngt,
    float* __restrict__ part1, int nb1, int M) {
  __shared__ float B[2304];  // 9.2 KB, reused across phases
  int t = threadIdx.x;
  long base = (long)blockIdx.x * TILE;
  float p[5] = {0.f, 0.f, 0.f, 0.f, 0.f};  // sdf, eik, morse, halign, inter

  int cntM = 0, cntN = 0;
  if (base < M) { long c = (long)M - base; cntM = c > TILE ? TILE : (int)c; }
  if (base < N) { long c = (long)N - base; cntN = c > TILE ? TILE : (int)c; }

  float prv = 0.f, mpv = 0.f, thv = 0.f;
  if (t < cntM) prv = pred[base + t];
  if (t < cntN) { mpv = mp[base + t]; thv = theta[base + t]; }

  // ---- phase A: pgrad | grad | ngt
  if (cntM > 0) stage_f(B, pgrad + 3 * base, 3 * cntM);
  __syncthreads();
  if (t < cntM) {
    float gx = B[3 * t], gy = B[3 * t + 1], gz = B[3 * t + 2];
    p[1] += fabsf(sqrtf(gx * gx + gy * gy + gz * gz) - 1.0f);
    p[4] += __expf(-100.0f * fabsf(prv));
  }
  __syncthreads();
  float ng0 = 0.f, ng1 = 0.f, ng2 = 0.f;
  if (cntN > 0) {
    stage_f(B, grad + 3 * base, 3 * cntN);
    stage_f(B + 768, ngt + 3 * base, 3 * cntN);
  }
  __syncthreads();
  if (t < cntN) {
    float gx = B[3 * t], gy = B[3 * t + 1], gz = B[3 * t + 2];
    p[1] += fabsf(sqrtf(gx * gx + gy * gy + gz * gz) - 1.0f);
    p[0] = fabsf(mpv);
    ng0 = B[768 + 3 * t]; ng1 = B[768 + 3 * t + 1]; ng2 = B[768 + 3 * t + 2];
  }
  __syncthreads();

  // ---- phase B: u | v -> crossfield, write vavb (nontemporal)
  if (cntN > 0) {
    stage_f(B, u + 3 * base, 3 * cntN);
    stage_f(B + 768, v + 3 * base, 3 * cntN);
  }
  __syncthreads();
  float va[3] = {0.f, 0.f, 0.f}, vb[3] = {0.f, 0.f, 0.f};
  if (t < cntN) {
    float s, c;
    __sincosf(thv, &s, &c);
    float ux = B[3 * t], uy = B[3 * t + 1], uz = B[3 * t + 2];
    float vx = B[768 + 3 * t], vy = B[768 + 3 * t + 1], vz = B[768 + 3 * t + 2];
    norm3(ux * c + vx * s, uy * c + vy * s, uz * c + vz * s, va[0], va[1], va[2]);
    norm3(vx * c - ux * s, vy * c - uy * s, vz * c - uz * s, vb[0], vb[1], vb[2]);
    VV o;
    o.h[0] = (_Float16)va[0]; o.h[1] = (_Float16)va[1]; o.h[2] = (_Float16)va[2];
    o.h[3] = (_Float16)vb[0]; o.h[4] = (_Float16)vb[1]; o.h[5] = (_Float16)vb[2];
    o.h[6] = (_Float16)0.f;   o.h[7] = (_Float16)0.f;
    nts4(&vavb[base + t], o.u4);
  }
  __syncthreads();

  // ---- phase C: H -> morse + hessian alignment
  if (cntN > 0) stage_f(B, H + 9 * base, 9 * cntN);
  __syncthreads();
  if (t < cntN) {
    float h[9];
#pragma unroll
    for (int q = 0; q < 9; ++q) h[q] = B[9 * t + q];
    p[2] = fabsf(ng0 * h[0] + ng1 * h[3] + ng2 * h[6]) +
           fabsf(ng0 * h[1] + ng1 * h[4] + ng2 * h[7]) +
           fabsf(ng0 * h[2] + ng1 * h[5] + ng2 * h[8]);
    float a0 = va[0] * h[0] + va[1] * h[3] + va[2] * h[6];
    float a1 = va[0] * h[1] + va[1] * h[4] + va[2] * h[7];
    float a2 = va[0] * h[2] + va[1] * h[5] + va[2] * h[8];
    float b0 = vb[0] * h[0] + vb[1] * h[3] + vb[2] * h[6];
    float b1 = vb[0] * h[1] + vb[1] * h[4] + vb[2] * h[7];
    float b2 = vb[0] * h[2] + vb[1] * h[5] + vb[2] * h[8];
    p[3] = fabsf(a1 * va[2] - a2 * va[1]) + fabsf(a2 * va[0] - a0 * va[2]) +
           fabsf(a0 * va[1] - a1 * va[0]) + fabsf(b1 * vb[2] - b2 * vb[1]) +
           fabsf(b2 * vb[0] - b0 * vb[2]) + fabsf(b0 * vb[1] - b1 * vb[0]);
  }

  block_reduce<5>(p);
  if (t == 0) {
#pragma unroll
    for (int q = 0; q < 5; ++q) part1[q * nb1 + blockIdx.x] = p[q];
  }
}

// ---- S3: neighbor consistency; rot staged per 128-vertex sub-tile ----------
__global__ __launch_bounds__(BLOCK) void s3_kernel(
    const u4v* __restrict__ vavb, const float* __restrict__ rot,
    const i4* __restrict__ nbr, float* __restrict__ part2, int N) {
  __shared__ float B[4608];  // 18.4 KB: rot for 128 vertices
  int t = threadIdx.x;
  long base = (long)blockIdx.x * TILE;
  int cntN = 0;
  if (base < N) { long c = (long)N - base; cntN = c > TILE ? TILE : (int)c; }
  float p[1] = {0.f};

  // issue scattered loads upfront (hide under staging)
  VV wn[4]; VV ws;
  ws.u4 = u4v{0, 0, 0, 0};
#pragma unroll
  for (int k = 0; k < KVAL; ++k) wn[k].u4 = u4v{0, 0, 0, 0};
  if (t < cntN) {
    i4 jj = nbr[base + t];
    int js[4] = {jj.x, jj.y, jj.z, jj.w};
#pragma unroll
    for (int k = 0; k < KVAL; ++k) wn[k].u4 = vavb[js[k]];
    ws.u4 = vavb[base + t];
  }
  float va[3] = {(float)ws.h[0], (float)ws.h[1], (float)ws.h[2]};
  float vb[3] = {(float)ws.h[3], (float)ws.h[4], (float)ws.h[5]};

  float nsum = 0.f;
#pragma unroll
  for (int sp = 0; sp < 2; ++sp) {
    int cs = cntN - 128 * sp;
    if (cs < 0) cs = 0;
    if (cs > 128) cs = 128;
    if (cs > 0) stage_f(B, rot + 36 * (base + 128 * sp), 36 * cs);
    __syncthreads();
    int lt = t - 128 * sp;
    if (lt >= 0 && lt < cs) {
      const float* R0 = B + 36 * lt;
#pragma unroll
      for (int k = 0; k < KVAL; ++k) {
        float R[9];
#pragma unroll
        for (int q = 0; q < 9; ++q) R[q] = R0[9 * k + q];
        // pa = R^T va, pb = R^T vb
        float pa0 = R[0] * va[0] + R[3] * va[1] + R[6] * va[2];
        float pa1 = R[1] * va[0] + R[4] * va[1] + R[7] * va[2];
        float pa2 = R[2] * va[0] + R[5] * va[1] + R[8] * va[2];
        float pb0 = R[0] * vb[0] + R[3] * vb[1] + R[6] * vb[2];
        float pb1 = R[1] * vb[0] + R[4] * vb[1] + R[7] * vb[2];
        float pb2 = R[2] * vb[0] + R[5] * vb[1] + R[8] * vb[2];
        float aj0 = (float)wn[k].h[0], aj1 = (float)wn[k].h[1],
              aj2 = (float)wn[k].h[2];
        float bj0 = (float)wn[k].h[3], bj1 = (float)wn[k].h[4],
              bj2 = (float)wn[k].h[5];
        nsum += fabsf(pa0 * aj0 + pa1 * aj1 + pa2 * aj2) +
                fabsf(pa0 * bj0 + pa1 * bj1 + pa2 * bj2) +
                fabsf(pb0 * aj0 + pb1 * aj1 + pb2 * aj2) +
                fabsf(pb0 * bj0 + pb1 * bj1 + pb2 * bj2) - 2.0f;
      }
    }
    __syncthreads();
  }
  p[0] = nsum;
  block_reduce<1>(p);
  if (t == 0) part2[blockIdx.x] = p[0];
}

// ---- finalize ---------------------------------------------------------------
__global__ __launch_bounds__(BLOCK) void finalize_fast(
    const float* __restrict__ part1, int nb1, const float* __restrict__ part2,
    int nb2, float* __restrict__ out, int N, int M) {
  float s[6] = {0.f, 0.f, 0.f, 0.f, 0.f, 0.f};
  for (int b = threadIdx.x; b < nb1; b += BLOCK) {
#pragma unroll
    for (int q = 0; q < 5; ++q) s[q] += part1[q * nb1 + b];
  }
  for (int b = threadIdx.x; b < nb2; b += BLOCK) s[5] += part2[b];
  block_reduce<6>(s);
  if (threadIdx.x == 0) {
    float sdf = s[0] / (float)N;
    float eik = s[1] / (float)(N + M);
    float morse = 0.5f * s[2] / (3.0f * (float)N);
    float th = 0.5f * s[3] / (3.0f * (float)N);
    float inter = s[4] / (float)M;
    float nb = s[5] / ((float)N * (float)KVAL);
    float loss = 7000.0f * sdf + 600.0f * inter + 50.0f * eik + 3.0f * morse +
                 10.0f * th + 30.0f * nb;
    out[0] = loss; out[1] = sdf; out[2] = inter; out[3] = eik;
    out[4] = morse; out[5] = th; out[6] = nb;
  }
}

// ---------------- fallback path (atomics, no ws tables) ---------------------
__device__ __forceinline__ void crossfield(const float* __restrict__ u,
                                           const float* __restrict__ v,
                                           const float* __restrict__ theta,
                                           int n, float va[3], float vb[3]) {
  float s, c;
  __sincosf(theta[n], &s, &c);
  float ux = u[3 * n], uy = u[3 * n + 1], uz = u[3 * n + 2];
  float vx = v[3 * n], vy = v[3 * n + 1], vz = v[3 * n + 2];
  norm3(ux * c + vx * s, uy * c + vy * s, uz * c + vz * s, va[0], va[1], va[2]);
  norm3(vx * c - ux * s, vy * c - uy * s, vz * c - uz * s, vb[0], vb[1], vb[2]);
}

__global__ __launch_bounds__(BLOCK) void vertex_kernel(
    const float* __restrict__ mp, const float* __restrict__ grad,
    const float* __restrict__ H, const float* __restrict__ ngt,
    const float* __restrict__ theta, const float* __restrict__ u,
    const float* __restrict__ v, const float* __restrict__ rot,
    const int* __restrict__ nbr, float* __restrict__ acc, int N) {
  int n = blockIdx.x * blockDim.x + threadIdx.x;
  float p[5] = {0.f, 0.f, 0.f, 0.f, 0.f};
  if (n < N) {
    float hh[9];
#pragma unroll
    for (int i = 0; i < 9; ++i) hh[i] = H[9 * (size_t)n + i];
    p[0] = fabsf(mp[n]);
    float gx = grad[3 * n], gy = grad[3 * n + 1], gz = grad[3 * n + 2];
    p[1] = fabsf(sqrtf(gx * gx + gy * gy + gz * gz) - 1.0f);
    float n0 = ngt[3 * n], n1 = ngt[3 * n + 1], n2 = ngt[3 * n + 2];
    p[2] = fabsf(n0 * hh[0] + n1 * hh[3] + n2 * hh[6]) +
           fabsf(n0 * hh[1] + n1 * hh[4] + n2 * hh[7]) +
           fabsf(n0 * hh[2] + n1 * hh[5] + n2 * hh[8]);
    float va[3], vb[3];
    crossfield(u, v, theta, n, va, vb);
    {
      float a0 = va[0] * hh[0] + va[1] * hh[3] + va[2] * hh[6];
      float a1 = va[0] * hh[1] + va[1] * hh[4] + va[2] * hh[7];
      float a2 = va[0] * hh[2] + va[1] * hh[5] + va[2] * hh[8];
      float b0 = vb[0] * hh[0] + vb[1] * hh[3] + vb[2] * hh[6];
      float b1 = vb[0] * hh[1] + vb[1] * hh[4] + vb[2] * hh[7];
      float b2 = vb[0] * hh[2] + vb[1] * hh[5] + vb[2] * hh[8];
      p[3] = fabsf(a1 * va[2] - a2 * va[1]) + fabsf(a2 * va[0] - a0 * va[2]) +
             fabsf(a0 * va[1] - a1 * va[0]) + fabsf(b1 * vb[2] - b2 * vb[1]) +
             fabsf(b2 * vb[0] - b0 * vb[2]) + fabsf(b0 * vb[1] - b1 * vb[0]);
    }
    float nsum = 0.f;
    const float* R = rot + (size_t)n * (KVAL * 9);
#pragma unroll
    for (int k = 0; k < KVAL; ++k) {
      int j = nbr[KVAL * (size_t)n + k];
      float vaj[3], vbj[3];
      crossfield(u, v, theta, j, vaj, vbj);
      float r0 = R[9 * k + 0], r1 = R[9 * k + 1], r2 = R[9 * k + 2];
      float r3 = R[9 * k + 3], r4 = R[9 * k + 4], r5 = R[9 * k + 5];
      float r6 = R[9 * k + 6], r7 = R[9 * k + 7], r8 = R[9 * k + 8];
      float wa0 = r0 * vaj[0] + r1 * vaj[1] + r2 * vaj[2];
      float wa1 = r3 * vaj[0] + r4 * vaj[1] + r5 * vaj[2];
      float wa2 = r6 * vaj[0] + r7 * vaj[1] + r8 * vaj[2];
      float wb0 = r0 * vbj[0] + r1 * vbj[1] + r2 * vbj[2];
      float wb1 = r3 * vbj[0] + r4 * vbj[1] + r5 * vbj[2];
      float wb2 = r6 * vbj[0] + r7 * vbj[1] + r8 * vbj[2];
      nsum += fabsf(va[0] * wa0 + va[1] * wa1 + va[2] * wa2) +
              fabsf(va[0] * wb0 + va[1] * wb1 + va[2] * wb2) +
              fabsf(vb[0] * wa0 + vb[1] * wa1 + vb[2] * wa2) +
              fabsf(vb[0] * wb0 + vb[1] * wb1 + vb[2] * wb2) - 2.0f;
    }
    p[4] = nsum;
  }
  block_reduce<5>(p);
  if (threadIdx.x == 0) {
    atomicAdd(&acc[0], p[0]); atomicAdd(&acc[1], p[1]); atomicAdd(&acc[2], p[2]);
    atomicAdd(&acc[3], p[3]); atomicAdd(&acc[4], p[4]);
  }
}

__global__ __launch_bounds__(BLOCK) void point_kernel(
    const float* __restrict__ pred, const float* __restrict__ grad,
    float* __restrict__ acc, int M) {
  int i = blockIdx.x * blockDim.x + threadIdx.x;
  float p[2] = {0.f, 0.f};
  if (i < M) {
    p[0] = __expf(-100.0f * fabsf(pred[i]));
    float gx = grad[3 * i], gy = grad[3 * i + 1], gz = grad[3 * i + 2];
    p[1] = fabsf(sqrtf(gx * gx + gy * gy + gz * gz) - 1.0f);
  }
  block_reduce<2>(p);
  if (threadIdx.x == 0) {
    atomicAdd(&acc[5], p[0]); atomicAdd(&acc[1], p[1]);
  }
}

__global__ void finalize_acc(const float* __restrict__ acc, float* __restrict__ out,
                             int N, int M) {
  if (threadIdx.x == 0 && blockIdx.x == 0) {
    float sdf = acc[0] / (float)N;
    float eik = acc[1] / (float)(N + M);
    float morse = 0.5f * acc[2] / (3.0f * (float)N);
    float th = 0.5f * acc[3] / (3.0f * (float)N);
    float nb = acc[4] / ((float)N * (float)KVAL);
    float inter = acc[5] / (float)M;
    float loss = 7000.0f * sdf + 600.0f * inter + 50.0f * eik + 3.0f * morse +
                 10.0f * th + 30.0f * nb;
    out[0] = loss; out[1] = sdf; out[2] = inter; out[3] = eik;
    out[4] = morse; out[5] = th; out[6] = nb;
  }
}

extern "C" void kernel_launch(void* const* d_in, const int* in_sizes, int n_in,
                              void* d_out, int out_size, void* d_ws, size_t ws_size,
                              hipStream_t stream) {
  const float* mp    = (const float*)d_in[0];
  const float* npred = (const float*)d_in[1];
  const float* grad  = (const float*)d_in[2];
  const float* ngrad = (const float*)d_in[3];
  const float* H     = (const float*)d_in[4];
  const float* ngt   = (const float*)d_in[5];
  const float* theta = (const float*)d_in[6];
  const float* u     = (const float*)d_in[7];
  const float* v     = (const float*)d_in[8];
  const float* rot   = (const float*)d_in[9];
  const int*   nbr   = (const int*)d_in[10];
  float* out = (float*)d_out;

  int N = in_sizes[0];
  int M = in_sizes[1];
  int mx = (N > M) ? N : M;
  int nb1 = (mx + TILE - 1) / TILE;   // s1 blocks
  int nb2 = (N + TILE - 1) / TILE;    // s3 blocks

  size_t off_vavb = 256;
  size_t off_p1 = off_vavb + (size_t)N * 16;
  size_t off_p2 = off_p1 + (size_t)5 * nb1 * 4;
  size_t need = off_p2 + (size_t)nb2 * 4;

  if (ws_size >= need) {
    u4v* vavb    = (u4v*)((char*)d_ws + off_vavb);
    float* part1 = (float*)((char*)d_ws + off_p1);
    float* part2 = (float*)((char*)d_ws + off_p2);
    s1_kernel<<<nb1, BLOCK, 0, stream>>>(
        theta, u, v, vavb, N, npred, ngrad, mp, grad, H, ngt, part1, nb1, M);
    s3_kernel<<<nb2, BLOCK, 0, stream>>>(
        vavb, rot, (const i4*)nbr, part2, N);
    finalize_fast<<<1, BLOCK, 0, stream>>>(part1, nb1, part2, nb2, out, N, M);
  } else {
    float* acc = (float*)d_ws;
    (void)hipMemsetAsync(acc, 0, 6 * sizeof(float), stream);
    vertex_kernel<<<(N + BLOCK - 1) / BLOCK, BLOCK, 0, stream>>>(
        mp, grad, H, ngt, theta, u, v, rot, nbr, acc, N);
    point_kernel<<<(M + BLOCK - 1) / BLOCK, BLOCK, 0, stream>>>(npred, ngrad, acc, M);
    finalize_acc<<<1, 64, 0, stream>>>(acc, out, N, M);
  }
}

// Round 14
// 59.774 us; speedup vs baseline: 1.0877x; 1.0011x over previous
//
#include <hip/hip_runtime.h>
#include <math.h>

static constexpr int BLOCK = 256;
static constexpr int WAVES = BLOCK / 64;
static constexpr int KVAL = 4;
static constexpr int TILE = 256;

typedef float f4 __attribute__((ext_vector_type(4)));
typedef int i4 __attribute__((ext_vector_type(4)));
typedef int i2 __attribute__((ext_vector_type(2)));
typedef unsigned int u4v __attribute__((ext_vector_type(4)));
union VV { u4v u4; _Float16 h[8]; };

__device__ __forceinline__ void nts4(u4v* p, u4v v) {
  __builtin_nontemporal_store(v, p);
}

__device__ __forceinline__ void norm3(float x, float y, float z,
                                      float& ox, float& oy, float& oz) {
  float inv = 1.0f / (sqrtf(x * x + y * y + z * z) + 1e-12f);
  ox = x * inv; oy = y * inv; oz = z * inv;
}

template <int NV>
__device__ __forceinline__ void block_reduce(float (&p)[NV]) {
#pragma unroll
  for (int off = 32; off > 0; off >>= 1)
#pragma unroll
    for (int q = 0; q < NV; ++q) p[q] += __shfl_down(p[q], off, 64);
  __shared__ float sm[WAVES][NV];
  int wave = threadIdx.x >> 6, lane = threadIdx.x & 63;
  if (lane == 0)
#pragma unroll
    for (int q = 0; q < NV; ++q) sm[wave][q] = p[q];
  __syncthreads();
  if (threadIdx.x == 0) {
#pragma unroll
    for (int q = 0; q < NV; ++q) {
      float t = 0.f;
#pragma unroll
      for (int w = 1; w < WAVES; ++w) t += sm[w][q];
      p[q] += t;
    }
  }
}

__device__ __forceinline__ void stage_f(float* __restrict__ dst,
                                        const float* __restrict__ src, int nf) {
  int t = threadIdx.x;
  int nf4 = nf >> 2;
  const f4* s4 = (const f4*)src;
  f4* d4 = (f4*)dst;
  for (int i = t; i < nf4; i += BLOCK) d4[i] = s4[i];
  int rem = nf & 3;
  if (t < rem) dst[nf4 * 4 + t] = src[nf4 * 4 + t];
}

// stage cs vertices' rot (36 floats each) into padded LDS (stride 37 floats)
__device__ __forceinline__ void stage_rot_pad(float* __restrict__ B,
                                              const float* __restrict__ src,
                                              int cs) {
  int nf4 = 9 * cs;  // 9 f4 per vertex
  const f4* s4 = (const f4*)src;
  for (int i = threadIdx.x; i < nf4; i += BLOCK) {
    f4 x = s4[i];
    int vtx = i / 9, r = i - 9 * vtx;
    float* d = B + vtx * 37 + r * 4;
    d[0] = x.x; d[1] = x.y; d[2] = x.z; d[3] = x.w;
  }
}

// ---- S1: streaming terms (no rot); 9.2 KB LDS, phased ----------------------
__global__ __launch_bounds__(BLOCK) void s1_kernel(
    const float* __restrict__ theta, const float* __restrict__ u,
    const float* __restrict__ v, u4v* __restrict__ vavb, int N,
    const float* __restrict__ pred, const float* __restrict__ pgrad,
    const float* __restrict__ mp, const float* __restrict__ grad,
    const float* __restrict__ H, const float* __restrict__ ngt,
    float* __restrict__ part1, int nb1, int M) {
  __shared__ float B[2304];
  int t = threadIdx.x;
  long base = (long)blockIdx.x * TILE;
  float p[5] = {0.f, 0.f, 0.f, 0.f, 0.f};  // sdf, eik, morse, halign, inter

  int cntM = 0, cntN = 0;
  if (base < M) { long c = (long)M - base; cntM = c > TILE ? TILE : (int)c; }
  if (base < N) { long c = (long)N - base; cntN = c > TILE ? TILE : (int)c; }

  float prv = 0.f, mpv = 0.f, thv = 0.f;
  if (t < cntM) prv = pred[base + t];
  if (t < cntN) { mpv = mp[base + t]; thv = theta[base + t]; }

  // ---- phase A: pgrad
  if (cntM > 0) stage_f(B, pgrad + 3 * base, 3 * cntM);
  __syncthreads();
  if (t < cntM) {
    float gx = B[3 * t], gy = B[3 * t + 1], gz = B[3 * t + 2];
    p[1] += fabsf(sqrtf(gx * gx + gy * gy + gz * gz) - 1.0f);
    p[4] += __expf(-100.0f * fabsf(prv));
  }
  __syncthreads();
  float ng0 = 0.f, ng1 = 0.f, ng2 = 0.f;
  if (cntN > 0) {
    stage_f(B, grad + 3 * base, 3 * cntN);
    stage_f(B + 768, ngt + 3 * base, 3 * cntN);
  }
  __syncthreads();
  if (t < cntN) {
    float gx = B[3 * t], gy = B[3 * t + 1], gz = B[3 * t + 2];
    p[1] += fabsf(sqrtf(gx * gx + gy * gy + gz * gz) - 1.0f);
    p[0] = fabsf(mpv);
    ng0 = B[768 + 3 * t]; ng1 = B[768 + 3 * t + 1]; ng2 = B[768 + 3 * t + 2];
  }
  __syncthreads();

  // ---- phase B: u | v -> crossfield
  if (cntN > 0) {
    stage_f(B, u + 3 * base, 3 * cntN);
    stage_f(B + 768, v + 3 * base, 3 * cntN);
  }
  __syncthreads();
  float va[3] = {0.f, 0.f, 0.f}, vb[3] = {0.f, 0.f, 0.f};
  if (t < cntN) {
    float s, c;
    __sincosf(thv, &s, &c);
    float ux = B[3 * t], uy = B[3 * t + 1], uz = B[3 * t + 2];
    float vx = B[768 + 3 * t], vy = B[768 + 3 * t + 1], vz = B[768 + 3 * t + 2];
    norm3(ux * c + vx * s, uy * c + vy * s, uz * c + vz * s, va[0], va[1], va[2]);
    norm3(vx * c - ux * s, vy * c - uy * s, vz * c - uz * s, vb[0], vb[1], vb[2]);
    VV o;
    o.h[0] = (_Float16)va[0]; o.h[1] = (_Float16)va[1]; o.h[2] = (_Float16)va[2];
    o.h[3] = (_Float16)vb[0]; o.h[4] = (_Float16)vb[1]; o.h[5] = (_Float16)vb[2];
    o.h[6] = (_Float16)0.f;   o.h[7] = (_Float16)0.f;
    nts4(&vavb[base + t], o.u4);
  }
  __syncthreads();

  // ---- phase C: H -> morse + hessian alignment
  if (cntN > 0) stage_f(B, H + 9 * base, 9 * cntN);
  __syncthreads();
  if (t < cntN) {
    float h[9];
#pragma unroll
    for (int q = 0; q < 9; ++q) h[q] = B[9 * t + q];
    p[2] = fabsf(ng0 * h[0] + ng1 * h[3] + ng2 * h[6]) +
           fabsf(ng0 * h[1] + ng1 * h[4] + ng2 * h[7]) +
           fabsf(ng0 * h[2] + ng1 * h[5] + ng2 * h[8]);
    float a0 = va[0] * h[0] + va[1] * h[3] + va[2] * h[6];
    float a1 = va[0] * h[1] + va[1] * h[4] + va[2] * h[7];
    float a2 = va[0] * h[2] + va[1] * h[5] + va[2] * h[8];
    float b0 = vb[0] * h[0] + vb[1] * h[3] + vb[2] * h[6];
    float b1 = vb[0] * h[1] + vb[1] * h[4] + vb[2] * h[7];
    float b2 = vb[0] * h[2] + vb[1] * h[5] + vb[2] * h[8];
    p[3] = fabsf(a1 * va[2] - a2 * va[1]) + fabsf(a2 * va[0] - a0 * va[2]) +
           fabsf(a0 * va[1] - a1 * va[0]) + fabsf(b1 * vb[2] - b2 * vb[1]) +
           fabsf(b2 * vb[0] - b0 * vb[2]) + fabsf(b0 * vb[1] - b1 * vb[0]);
  }

  block_reduce<5>(p);
  if (t == 0) {
#pragma unroll
    for (int q = 0; q < 5; ++q) part1[q * nb1 + blockIdx.x] = p[q];
  }
}

// ---- S3: neighbor consistency; pair-split, padded conflict-free LDS --------
__global__ __launch_bounds__(BLOCK) void s3_kernel(
    const u4v* __restrict__ vavb, const float* __restrict__ rot,
    const i2* __restrict__ nbr2, float* __restrict__ part2, int N) {
  __shared__ float B[128 * 37];  // 18.9 KB
  int t = threadIdx.x;
  int vl = t >> 1;       // local vertex within sub-tile (0..127)
  int h = t & 1;         // half: owns k = 2h, 2h+1
  long base = (long)blockIdx.x * TILE;
  int cntN = 0;
  if (base < N) { long c = (long)N - base; cntN = c > TILE ? TILE : (int)c; }

  // issue all scattered loads for both sub-tiles upfront
  VV wn[2][2]; VV ws[2];
#pragma unroll
  for (int sp = 0; sp < 2; ++sp) {
    ws[sp].u4 = u4v{0, 0, 0, 0};
    wn[sp][0].u4 = u4v{0, 0, 0, 0};
    wn[sp][1].u4 = u4v{0, 0, 0, 0};
    int lv = 128 * sp + vl;
    if (lv < cntN) {
      long n = base + lv;
      i2 jj = nbr2[2 * n + h];   // coalesced 8B: ints 2h, 2h+1
      wn[sp][0].u4 = vavb[jj.x];
      wn[sp][1].u4 = vavb[jj.y];
      ws[sp].u4 = vavb[n];
    }
  }

  float nsum = 0.f;
#pragma unroll
  for (int sp = 0; sp < 2; ++sp) {
    int cs = cntN - 128 * sp;
    if (cs < 0) cs = 0;
    if (cs > 128) cs = 128;
    if (cs > 0) stage_rot_pad(B, rot + 36 * (base + 128 * sp), cs);
    __syncthreads();
    if (vl < cs) {
      float va[3] = {(float)ws[sp].h[0], (float)ws[sp].h[1], (float)ws[sp].h[2]};
      float vb[3] = {(float)ws[sp].h[3], (float)ws[sp].h[4], (float)ws[sp].h[5]};
      const float* R0 = B + 37 * vl;
#pragma unroll
      for (int kk = 0; kk < 2; ++kk) {
        int k = 2 * h + kk;
        float R[9];
#pragma unroll
        for (int q = 0; q < 9; ++q) R[q] = R0[9 * k + q];
        float pa0 = R[0] * va[0] + R[3] * va[1] + R[6] * va[2];
        float pa1 = R[1] * va[0] + R[4] * va[1] + R[7] * va[2];
        float pa2 = R[2] * va[0] + R[5] * va[1] + R[8] * va[2];
        float pb0 = R[0] * vb[0] + R[3] * vb[1] + R[6] * vb[2];
        float pb1 = R[1] * vb[0] + R[4] * vb[1] + R[7] * vb[2];
        float pb2 = R[2] * vb[0] + R[5] * vb[1] + R[8] * vb[2];
        float aj0 = (float)wn[sp][kk].h[0], aj1 = (float)wn[sp][kk].h[1],
              aj2 = (float)wn[sp][kk].h[2];
        float bj0 = (float)wn[sp][kk].h[3], bj1 = (float)wn[sp][kk].h[4],
              bj2 = (float)wn[sp][kk].h[5];
        nsum += fabsf(pa0 * aj0 + pa1 * aj1 + pa2 * aj2) +
                fabsf(pa0 * bj0 + pa1 * bj1 + pa2 * bj2) +
                fabsf(pb0 * aj0 + pb1 * aj1 + pb2 * aj2) +
                fabsf(pb0 * bj0 + pb1 * bj1 + pb2 * bj2) - 2.0f;
      }
    }
    __syncthreads();
  }
  float p[1] = {nsum};
  block_reduce<1>(p);
  if (t == 0) part2[blockIdx.x] = p[0];
}

// ---- finalize ---------------------------------------------------------------
__global__ __launch_bounds__(BLOCK) void finalize_fast(
    const float* __restrict__ part1, int nb1, const float* __restrict__ part2,
    int nb2, float* __restrict__ out, int N, int M) {
  float s[6] = {0.f, 0.f, 0.f, 0.f, 0.f, 0.f};
  for (int b = threadIdx.x; b < nb1; b += BLOCK) {
#pragma unroll
    for (int q = 0; q < 5; ++q) s[q] += part1[q * nb1 + b];
  }
  for (int b = threadIdx.x; b < nb2; b += BLOCK) s[5] += part2[b];
  block_reduce<6>(s);
  if (threadIdx.x == 0) {
    float sdf = s[0] / (float)N;
    float eik = s[1] / (float)(N + M);
    float morse = 0.5f * s[2] / (3.0f * (float)N);
    float th = 0.5f * s[3] / (3.0f * (float)N);
    float inter = s[4] / (float)M;
    float nb = s[5] / ((float)N * (float)KVAL);
    float loss = 7000.0f * sdf + 600.0f * inter + 50.0f * eik + 3.0f * morse +
                 10.0f * th + 30.0f * nb;
    out[0] = loss; out[1] = sdf; out[2] = inter; out[3] = eik;
    out[4] = morse; out[5] = th; out[6] = nb;
  }
}

// ---------------- fallback path (atomics, no ws tables) ---------------------
__device__ __forceinline__ void crossfield(const float* __restrict__ u,
                                           const float* __restrict__ v,
                                           const float* __restrict__ theta,
                                           int n, float va[3], float vb[3]) {
  float s, c;
  __sincosf(theta[n], &s, &c);
  float ux = u[3 * n], uy = u[3 * n + 1], uz = u[3 * n + 2];
  float vx = v[3 * n], vy = v[3 * n + 1], vz = v[3 * n + 2];
  norm3(ux * c + vx * s, uy * c + vy * s, uz * c + vz * s, va[0], va[1], va[2]);
  norm3(vx * c - ux * s, vy * c - uy * s, vz * c - uz * s, vb[0], vb[1], vb[2]);
}

__global__ __launch_bounds__(BLOCK) void vertex_kernel(
    const float* __restrict__ mp, const float* __restrict__ grad,
    const float* __restrict__ H, const float* __restrict__ ngt,
    const float* __restrict__ theta, const float* __restrict__ u,
    const float* __restrict__ v, const float* __restrict__ rot,
    const int* __restrict__ nbr, float* __restrict__ acc, int N) {
  int n = blockIdx.x * blockDim.x + threadIdx.x;
  float p[5] = {0.f, 0.f, 0.f, 0.f, 0.f};
  if (n < N) {
    float hh[9];
#pragma unroll
    for (int i = 0; i < 9; ++i) hh[i] = H[9 * (size_t)n + i];
    p[0] = fabsf(mp[n]);
    float gx = grad[3 * n], gy = grad[3 * n + 1], gz = grad[3 * n + 2];
    p[1] = fabsf(sqrtf(gx * gx + gy * gy + gz * gz) - 1.0f);
    float n0 = ngt[3 * n], n1 = ngt[3 * n + 1], n2 = ngt[3 * n + 2];
    p[2] = fabsf(n0 * hh[0] + n1 * hh[3] + n2 * hh[6]) +
           fabsf(n0 * hh[1] + n1 * hh[4] + n2 * hh[7]) +
           fabsf(n0 * hh[2] + n1 * hh[5] + n2 * hh[8]);
    float va[3], vb[3];
    crossfield(u, v, theta, n, va, vb);
    {
      float a0 = va[0] * hh[0] + va[1] * hh[3] + va[2] * hh[6];
      float a1 = va[0] * hh[1] + va[1] * hh[4] + va[2] * hh[7];
      float a2 = va[0] * hh[2] + va[1] * hh[5] + va[2] * hh[8];
      float b0 = vb[0] * hh[0] + vb[1] * hh[3] + vb[2] * hh[6];
      float b1 = vb[0] * hh[1] + vb[1] * hh[4] + vb[2] * hh[7];
      float b2 = vb[0] * hh[2] + vb[1] * hh[5] + vb[2] * hh[8];
      p[3] = fabsf(a1 * va[2] - a2 * va[1]) + fabsf(a2 * va[0] - a0 * va[2]) +
             fabsf(a0 * va[1] - a1 * va[0]) + fabsf(b1 * vb[2] - b2 * vb[1]) +
             fabsf(b2 * vb[0] - b0 * vb[2]) + fabsf(b0 * vb[1] - b1 * vb[0]);
    }
    float nsum = 0.f;
    const float* R = rot + (size_t)n * (KVAL * 9);
#pragma unroll
    for (int k = 0; k < KVAL; ++k) {
      int j = nbr[KVAL * (size_t)n + k];
      float vaj[3], vbj[3];
      crossfield(u, v, theta, j, vaj, vbj);
      float r0 = R[9 * k + 0], r1 = R[9 * k + 1], r2 = R[9 * k + 2];
      float r3 = R[9 * k + 3], r4 = R[9 * k + 4], r5 = R[9 * k + 5];
      float r6 = R[9 * k + 6], r7 = R[9 * k + 7], r8 = R[9 * k + 8];
      float wa0 = r0 * vaj[0] + r1 * vaj[1] + r2 * vaj[2];
      float wa1 = r3 * vaj[0] + r4 * vaj[1] + r5 * vaj[2];
      float wa2 = r6 * vaj[0] + r7 * vaj[1] + r8 * vaj[2];
      float wb0 = r0 * vbj[0] + r1 * vbj[1] + r2 * vbj[2];
      float wb1 = r3 * vbj[0] + r4 * vbj[1] + r5 * vbj[2];
      float wb2 = r6 * vbj[0] + r7 * vbj[1] + r8 * vbj[2];
      nsum += fabsf(va[0] * wa0 + va[1] * wa1 + va[2] * wa2) +
              fabsf(va[0] * wb0 + va[1] * wb1 + va[2] * wb2) +
              fabsf(vb[0] * wa0 + vb[1] * wa1 + vb[2] * wa2) +
              fabsf(vb[0] * wb0 + vb[1] * wb1 + vb[2] * wb2) - 2.0f;
    }
    p[4] = nsum;
  }
  block_reduce<5>(p);
  if (threadIdx.x == 0) {
    atomicAdd(&acc[0], p[0]); atomicAdd(&acc[1], p[1]); atomicAdd(&acc[2], p[2]);
    atomicAdd(&acc[3], p[3]); atomicAdd(&acc[4], p[4]);
  }
}

__global__ __launch_bounds__(BLOCK) void point_kernel(
    const float* __restrict__ pred, const float* __restrict__ grad,
    float* __restrict__ acc, int M) {
  int i = blockIdx.x * blockDim.x + threadIdx.x;
  float p[2] = {0.f, 0.f};
  if (i < M) {
    p[0] = __expf(-100.0f * fabsf(pred[i]));
    float gx = grad[3 * i], gy = grad[3 * i + 1], gz = grad[3 * i + 2];
    p[1] = fabsf(sqrtf(gx * gx + gy * gy + gz * gz) - 1.0f);
  }
  block_reduce<2>(p);
  if (threadIdx.x == 0) {
    atomicAdd(&acc[5], p[0]); atomicAdd(&acc[1], p[1]);
  }
}

__global__ void finalize_acc(const float* __restrict__ acc, float* __restrict__ out,
                             int N, int M) {
  if (threadIdx.x == 0 && blockIdx.x == 0) {
    float sdf = acc[0] / (float)N;
    float eik = acc[1] / (float)(N + M);
    float morse = 0.5f * acc[2] / (3.0f * (float)N);
    float th = 0.5f * acc[3] / (3.0f * (float)N);
    float nb = acc[4] / ((float)N * (float)KVAL);
    float inter = acc[5] / (float)M;
    float loss = 7000.0f * sdf + 600.0f * inter + 50.0f * eik + 3.0f * morse +
                 10.0f * th + 30.0f * nb;
    out[0] = loss; out[1] = sdf; out[2] = inter; out[3] = eik;
    out[4] = morse; out[5] = th; out[6] = nb;
  }
}

extern "C" void kernel_launch(void* const* d_in, const int* in_sizes, int n_in,
                              void* d_out, int out_size, void* d_ws, size_t ws_size,
                              hipStream_t stream) {
  const float* mp    = (const float*)d_in[0];
  const float* npred = (const float*)d_in[1];
  const float* grad  = (const float*)d_in[2];
  const float* ngrad = (const float*)d_in[3];
  const float* H     = (const float*)d_in[4];
  const float* ngt   = (const float*)d_in[5];
  const float* theta = (const float*)d_in[6];
  const float* u     = (const float*)d_in[7];
  const float* v     = (const float*)d_in[8];
  const float* rot   = (const float*)d_in[9];
  const int*   nbr   = (const int*)d_in[10];
  float* out = (float*)d_out;

  int N = in_sizes[0];
  int M = in_sizes[1];
  int mx = (N > M) ? N : M;
  int nb1 = (mx + TILE - 1) / TILE;
  int nb2 = (N + TILE - 1) / TILE;

  size_t off_vavb = 256;
  size_t off_p1 = off_vavb + (size_t)N * 16;
  size_t off_p2 = off_p1 + (size_t)5 * nb1 * 4;
  size_t need = off_p2 + (size_t)nb2 * 4;

  if (ws_size >= need) {
    u4v* vavb    = (u4v*)((char*)d_ws + off_vavb);
    float* part1 = (float*)((char*)d_ws + off_p1);
    float* part2 = (float*)((char*)d_ws + off_p2);
    s1_kernel<<<nb1, BLOCK, 0, stream>>>(
        theta, u, v, vavb, N, npred, ngrad, mp, grad, H, ngt, part1, nb1, M);
    s3_kernel<<<nb2, BLOCK, 0, stream>>>(
        vavb, rot, (const i2*)nbr, part2, N);
    finalize_fast<<<1, BLOCK, 0, stream>>>(part1, nb1, part2, nb2, out, N, M);
  } else {
    float* acc = (float*)d_ws;
    (void)hipMemsetAsync(acc, 0, 6 * sizeof(float), stream);
    vertex_kernel<<<(N + BLOCK - 1) / BLOCK, BLOCK, 0, stream>>>(
        mp, grad, H, ngt, theta, u, v, rot, nbr, acc, N);
    point_kernel<<<(M + BLOCK - 1) / BLOCK, BLOCK, 0, stream>>>(npred, ngrad, acc, M);
    finalize_acc<<<1, 64, 0, stream>>>(acc, out, N, M);
  }
}

// Round 15
// 52.461 us; speedup vs baseline: 1.2393x; 1.1394x over previous
//
#include <hip/hip_runtime.h>
#include <math.h>

static constexpr int BLOCK = 256;
static constexpr int WAVES = BLOCK / 64;
static constexpr int KVAL = 4;
static constexpr int TILE = 256;

typedef float f4 __attribute__((ext_vector_type(4)));
typedef int i4 __attribute__((ext_vector_type(4)));
typedef int i2 __attribute__((ext_vector_type(2)));
typedef unsigned int u2v __attribute__((ext_vector_type(2)));

__device__ __forceinline__ void norm3(float x, float y, float z,
                                      float& ox, float& oy, float& oz) {
  float inv = 1.0f / (sqrtf(x * x + y * y + z * z) + 1e-12f);
  ox = x * inv; oy = y * inv; oz = z * inv;
}

template <int NV>
__device__ __forceinline__ void block_reduce(float (&p)[NV]) {
#pragma unroll
  for (int off = 32; off > 0; off >>= 1)
#pragma unroll
    for (int q = 0; q < NV; ++q) p[q] += __shfl_down(p[q], off, 64);
  __shared__ float sm[WAVES][NV];
  int wave = threadIdx.x >> 6, lane = threadIdx.x & 63;
  if (lane == 0)
#pragma unroll
    for (int q = 0; q < NV; ++q) sm[wave][q] = p[q];
  __syncthreads();
  if (threadIdx.x == 0) {
#pragma unroll
    for (int q = 0; q < NV; ++q) {
      float t = 0.f;
#pragma unroll
      for (int w = 1; w < WAVES; ++w) t += sm[w][q];
      p[q] += t;
    }
  }
}

__device__ __forceinline__ void stage_f(float* __restrict__ dst,
                                        const float* __restrict__ src, int nf) {
  int t = threadIdx.x;
  int nf4 = nf >> 2;
  const f4* s4 = (const f4*)src;
  f4* d4 = (f4*)dst;
  for (int i = t; i < nf4; i += BLOCK) d4[i] = s4[i];
  int rem = nf & 3;
  if (t < rem) dst[nf4 * 4 + t] = src[nf4 * 4 + t];
}

// stage cs vertices' rot into padded LDS (stride 37 floats), nontemporal reads
__device__ __forceinline__ void stage_rot_pad(float* __restrict__ B,
                                              const float* __restrict__ src,
                                              int cs) {
  int nf4 = 9 * cs;
  const f4* s4 = (const f4*)src;
  for (int i = threadIdx.x; i < nf4; i += BLOCK) {
    f4 x = __builtin_nontemporal_load(s4 + i);
    int vtx = i / 9, r = i - 9 * vtx;
    float* d = B + vtx * 37 + r * 4;
    d[0] = x.x; d[1] = x.y; d[2] = x.z; d[3] = x.w;
  }
}

// unpack 6 x fp8 (bytes: va0 va1 va2 vb0 | vb1 vb2 - -) -> floats
__device__ __forceinline__ void unpack8(u2v w, float* va, float* vb) {
  va[0] = __builtin_amdgcn_cvt_f32_fp8((int)w.x, 0);
  va[1] = __builtin_amdgcn_cvt_f32_fp8((int)w.x, 1);
  va[2] = __builtin_amdgcn_cvt_f32_fp8((int)w.x, 2);
  vb[0] = __builtin_amdgcn_cvt_f32_fp8((int)w.x, 3);
  vb[1] = __builtin_amdgcn_cvt_f32_fp8((int)w.y, 0);
  vb[2] = __builtin_amdgcn_cvt_f32_fp8((int)w.y, 1);
}

// ---- S1: streaming terms; writes fp8-packed vavb (8 B/vertex) --------------
__global__ __launch_bounds__(BLOCK) void s1_kernel(
    const float* __restrict__ theta, const float* __restrict__ u,
    const float* __restrict__ v, u2v* __restrict__ vavb8, int N,
    const float* __restrict__ pred, const float* __restrict__ pgrad,
    const float* __restrict__ mp, const float* __restrict__ grad,
    const float* __restrict__ H, const float* __restrict__ ngt,
    float* __restrict__ part1, int nb1, int M) {
  __shared__ float B[2304];
  int t = threadIdx.x;
  long base = (long)blockIdx.x * TILE;
  float p[5] = {0.f, 0.f, 0.f, 0.f, 0.f};  // sdf, eik, morse, halign, inter

  int cntM = 0, cntN = 0;
  if (base < M) { long c = (long)M - base; cntM = c > TILE ? TILE : (int)c; }
  if (base < N) { long c = (long)N - base; cntN = c > TILE ? TILE : (int)c; }

  float prv = 0.f, mpv = 0.f, thv = 0.f;
  if (t < cntM) prv = pred[base + t];
  if (t < cntN) { mpv = mp[base + t]; thv = theta[base + t]; }

  // ---- phase A: pgrad, then grad | ngt
  if (cntM > 0) stage_f(B, pgrad + 3 * base, 3 * cntM);
  __syncthreads();
  if (t < cntM) {
    float gx = B[3 * t], gy = B[3 * t + 1], gz = B[3 * t + 2];
    p[1] += fabsf(sqrtf(gx * gx + gy * gy + gz * gz) - 1.0f);
    p[4] += __expf(-100.0f * fabsf(prv));
  }
  __syncthreads();
  float ng0 = 0.f, ng1 = 0.f, ng2 = 0.f;
  if (cntN > 0) {
    stage_f(B, grad + 3 * base, 3 * cntN);
    stage_f(B + 768, ngt + 3 * base, 3 * cntN);
  }
  __syncthreads();
  if (t < cntN) {
    float gx = B[3 * t], gy = B[3 * t + 1], gz = B[3 * t + 2];
    p[1] += fabsf(sqrtf(gx * gx + gy * gy + gz * gz) - 1.0f);
    p[0] = fabsf(mpv);
    ng0 = B[768 + 3 * t]; ng1 = B[768 + 3 * t + 1]; ng2 = B[768 + 3 * t + 2];
  }
  __syncthreads();

  // ---- phase B: u | v -> crossfield, write fp8 vavb
  if (cntN > 0) {
    stage_f(B, u + 3 * base, 3 * cntN);
    stage_f(B + 768, v + 3 * base, 3 * cntN);
  }
  __syncthreads();
  float va[3] = {0.f, 0.f, 0.f}, vb[3] = {0.f, 0.f, 0.f};
  if (t < cntN) {
    float s, c;
    __sincosf(thv, &s, &c);
    float ux = B[3 * t], uy = B[3 * t + 1], uz = B[3 * t + 2];
    float vx = B[768 + 3 * t], vy = B[768 + 3 * t + 1], vz = B[768 + 3 * t + 2];
    norm3(ux * c + vx * s, uy * c + vy * s, uz * c + vz * s, va[0], va[1], va[2]);
    norm3(vx * c - ux * s, vy * c - uy * s, vz * c - uz * s, vb[0], vb[1], vb[2]);
    unsigned int w0 = (unsigned)__builtin_amdgcn_cvt_pk_fp8_f32(va[0], va[1], 0, false);
    w0 = (unsigned)__builtin_amdgcn_cvt_pk_fp8_f32(va[2], vb[0], (int)w0, true);
    unsigned int w1 = (unsigned)__builtin_amdgcn_cvt_pk_fp8_f32(vb[1], vb[2], 0, false);
    u2v o; o.x = w0; o.y = w1;
    __builtin_nontemporal_store(o, &vavb8[base + t]);
  }
  __syncthreads();

  // ---- phase C: H -> morse + hessian alignment (exact f32 va/vb)
  if (cntN > 0) stage_f(B, H + 9 * base, 9 * cntN);
  __syncthreads();
  if (t < cntN) {
    float h[9];
#pragma unroll
    for (int q = 0; q < 9; ++q) h[q] = B[9 * t + q];
    p[2] = fabsf(ng0 * h[0] + ng1 * h[3] + ng2 * h[6]) +
           fabsf(ng0 * h[1] + ng1 * h[4] + ng2 * h[7]) +
           fabsf(ng0 * h[2] + ng1 * h[5] + ng2 * h[8]);
    float a0 = va[0] * h[0] + va[1] * h[3] + va[2] * h[6];
    float a1 = va[0] * h[1] + va[1] * h[4] + va[2] * h[7];
    float a2 = va[0] * h[2] + va[1] * h[5] + va[2] * h[8];
    float b0 = vb[0] * h[0] + vb[1] * h[3] + vb[2] * h[6];
    float b1 = vb[0] * h[1] + vb[1] * h[4] + vb[2] * h[7];
    float b2 = vb[0] * h[2] + vb[1] * h[5] + vb[2] * h[8];
    p[3] = fabsf(a1 * va[2] - a2 * va[1]) + fabsf(a2 * va[0] - a0 * va[2]) +
           fabsf(a0 * va[1] - a1 * va[0]) + fabsf(b1 * vb[2] - b2 * vb[1]) +
           fabsf(b2 * vb[0] - b0 * vb[2]) + fabsf(b0 * vb[1] - b1 * vb[0]);
  }

  block_reduce<5>(p);
  if (t == 0) {
#pragma unroll
    for (int q = 0; q < 5; ++q) part1[q * nb1 + blockIdx.x] = p[q];
  }
}

// ---- S3: neighbor consistency; fp8 gathers (L2-resident 4 MB table) --------
__global__ __launch_bounds__(BLOCK) void s3_kernel(
    const u2v* __restrict__ vavb8, const float* __restrict__ rot,
    const i2* __restrict__ nbr2, float* __restrict__ part2, int N) {
  __shared__ float B[128 * 37];  // 18.9 KB
  int t = threadIdx.x;
  int vl = t >> 1;  // local vertex (0..127)
  int h = t & 1;    // half: owns k = 2h, 2h+1
  long base = (long)blockIdx.x * TILE;
  int cntN = 0;
  if (base < N) { long c = (long)N - base; cntN = c > TILE ? TILE : (int)c; }

  // issue all scattered loads for both sub-tiles upfront (cacheable - want L2)
  u2v wn[2][2]; u2v ws[2];
#pragma unroll
  for (int sp = 0; sp < 2; ++sp) {
    ws[sp] = u2v{0, 0};
    wn[sp][0] = u2v{0, 0};
    wn[sp][1] = u2v{0, 0};
    int lv = 128 * sp + vl;
    if (lv < cntN) {
      long n = base + lv;
      i2 jj = __builtin_nontemporal_load(&nbr2[2 * n + h]);
      wn[sp][0] = vavb8[jj.x];
      wn[sp][1] = vavb8[jj.y];
      ws[sp] = vavb8[n];
    }
  }

  float nsum = 0.f;
#pragma unroll
  for (int sp = 0; sp < 2; ++sp) {
    int cs = cntN - 128 * sp;
    if (cs < 0) cs = 0;
    if (cs > 128) cs = 128;
    if (cs > 0) stage_rot_pad(B, rot + 36 * (base + 128 * sp), cs);
    __syncthreads();
    if (vl < cs) {
      float va[3], vb[3];
      unpack8(ws[sp], va, vb);
      const float* R0 = B + 37 * vl;
#pragma unroll
      for (int kk = 0; kk < 2; ++kk) {
        int k = 2 * h + kk;
        float R[9];
#pragma unroll
        for (int q = 0; q < 9; ++q) R[q] = R0[9 * k + q];
        float pa0 = R[0] * va[0] + R[3] * va[1] + R[6] * va[2];
        float pa1 = R[1] * va[0] + R[4] * va[1] + R[7] * va[2];
        float pa2 = R[2] * va[0] + R[5] * va[1] + R[8] * va[2];
        float pb0 = R[0] * vb[0] + R[3] * vb[1] + R[6] * vb[2];
        float pb1 = R[1] * vb[0] + R[4] * vb[1] + R[7] * vb[2];
        float pb2 = R[2] * vb[0] + R[5] * vb[1] + R[8] * vb[2];
        float aj[3], bj[3];
        unpack8(wn[sp][kk], aj, bj);
        nsum += fabsf(pa0 * aj[0] + pa1 * aj[1] + pa2 * aj[2]) +
                fabsf(pa0 * bj[0] + pa1 * bj[1] + pa2 * bj[2]) +
                fabsf(pb0 * aj[0] + pb1 * aj[1] + pb2 * aj[2]) +
                fabsf(pb0 * bj[0] + pb1 * bj[1] + pb2 * bj[2]) - 2.0f;
      }
    }
    __syncthreads();
  }
  float p[1] = {nsum};
  block_reduce<1>(p);
  if (t == 0) part2[blockIdx.x] = p[0];
}

// ---- finalize ---------------------------------------------------------------
__global__ __launch_bounds__(BLOCK) void finalize_fast(
    const float* __restrict__ part1, int nb1, const float* __restrict__ part2,
    int nb2, float* __restrict__ out, int N, int M) {
  float s[6] = {0.f, 0.f, 0.f, 0.f, 0.f, 0.f};
  for (int b = threadIdx.x; b < nb1; b += BLOCK) {
#pragma unroll
    for (int q = 0; q < 5; ++q) s[q] += part1[q * nb1 + b];
  }
  for (int b = threadIdx.x; b < nb2; b += BLOCK) s[5] += part2[b];
  block_reduce<6>(s);
  if (threadIdx.x == 0) {
    float sdf = s[0] / (float)N;
    float eik = s[1] / (float)(N + M);
    float morse = 0.5f * s[2] / (3.0f * (float)N);
    float th = 0.5f * s[3] / (3.0f * (float)N);
    float inter = s[4] / (float)M;
    float nb = s[5] / ((float)N * (float)KVAL);
    float loss = 7000.0f * sdf + 600.0f * inter + 50.0f * eik + 3.0f * morse +
                 10.0f * th + 30.0f * nb;
    out[0] = loss; out[1] = sdf; out[2] = inter; out[3] = eik;
    out[4] = morse; out[5] = th; out[6] = nb;
  }
}

// ---------------- fallback path (atomics, no ws tables) ---------------------
__device__ __forceinline__ void crossfield(const float* __restrict__ u,
                                           const float* __restrict__ v,
                                           const float* __restrict__ theta,
                                           int n, float va[3], float vb[3]) {
  float s, c;
  __sincosf(theta[n], &s, &c);
  float ux = u[3 * n], uy = u[3 * n + 1], uz = u[3 * n + 2];
  float vx = v[3 * n], vy = v[3 * n + 1], vz = v[3 * n + 2];
  norm3(ux * c + vx * s, uy * c + vy * s, uz * c + vz * s, va[0], va[1], va[2]);
  norm3(vx * c - ux * s, vy * c - uy * s, vz * c - uz * s, vb[0], vb[1], vb[2]);
}

__global__ __launch_bounds__(BLOCK) void vertex_kernel(
    const float* __restrict__ mp, const float* __restrict__ grad,
    const float* __restrict__ H, const float* __restrict__ ngt,
    const float* __restrict__ theta, const float* __restrict__ u,
    const float* __restrict__ v, const float* __restrict__ rot,
    const int* __restrict__ nbr, float* __restrict__ acc, int N) {
  int n = blockIdx.x * blockDim.x + threadIdx.x;
  float p[5] = {0.f, 0.f, 0.f, 0.f, 0.f};
  if (n < N) {
    float hh[9];
#pragma unroll
    for (int i = 0; i < 9; ++i) hh[i] = H[9 * (size_t)n + i];
    p[0] = fabsf(mp[n]);
    float gx = grad[3 * n], gy = grad[3 * n + 1], gz = grad[3 * n + 2];
    p[1] = fabsf(sqrtf(gx * gx + gy * gy + gz * gz) - 1.0f);
    float n0 = ngt[3 * n], n1 = ngt[3 * n + 1], n2 = ngt[3 * n + 2];
    p[2] = fabsf(n0 * hh[0] + n1 * hh[3] + n2 * hh[6]) +
           fabsf(n0 * hh[1] + n1 * hh[4] + n2 * hh[7]) +
           fabsf(n0 * hh[2] + n1 * hh[5] + n2 * hh[8]);
    float va[3], vb[3];
    crossfield(u, v, theta, n, va, vb);
    {
      float a0 = va[0] * hh[0] + va[1] * hh[3] + va[2] * hh[6];
      float a1 = va[0] * hh[1] + va[1] * hh[4] + va[2] * hh[7];
      float a2 = va[0] * hh[2] + va[1] * hh[5] + va[2] * hh[8];
      float b0 = vb[0] * hh[0] + vb[1] * hh[3] + vb[2] * hh[6];
      float b1 = vb[0] * hh[1] + vb[1] * hh[4] + vb[2] * hh[7];
      float b2 = vb[0] * hh[2] + vb[1] * hh[5] + vb[2] * hh[8];
      p[3] = fabsf(a1 * va[2] - a2 * va[1]) + fabsf(a2 * va[0] - a0 * va[2]) +
             fabsf(a0 * va[1] - a1 * va[0]) + fabsf(b1 * vb[2] - b2 * vb[1]) +
             fabsf(b2 * vb[0] - b0 * vb[2]) + fabsf(b0 * vb[1] - b1 * vb[0]);
    }
    float nsum = 0.f;
    const float* R = rot + (size_t)n * (KVAL * 9);
#pragma unroll
    for (int k = 0; k < KVAL; ++k) {
      int j = nbr[KVAL * (size_t)n + k];
      float vaj[3], vbj[3];
      crossfield(u, v, theta, j, vaj, vbj);
      float r0 = R[9 * k + 0], r1 = R[9 * k + 1], r2 = R[9 * k + 2];
      float r3 = R[9 * k + 3], r4 = R[9 * k + 4], r5 = R[9 * k + 5];
      float r6 = R[9 * k + 6], r7 = R[9 * k + 7], r8 = R[9 * k + 8];
      float wa0 = r0 * vaj[0] + r1 * vaj[1] + r2 * vaj[2];
      float wa1 = r3 * vaj[0] + r4 * vaj[1] + r5 * vaj[2];
      float wa2 = r6 * vaj[0] + r7 * vaj[1] + r8 * vaj[2];
      float wb0 = r0 * vbj[0] + r1 * vbj[1] + r2 * vbj[2];
      float wb1 = r3 * vbj[0] + r4 * vbj[1] + r5 * vbj[2];
      float wb2 = r6 * vbj[0] + r7 * vbj[1] + r8 * vbj[2];
      nsum += fabsf(va[0] * wa0 + va[1] * wa1 + va[2] * wa2) +
              fabsf(va[0] * wb0 + va[1] * wb1 + va[2] * wb2) +
              fabsf(vb[0] * wa0 + vb[1] * wa1 + vb[2] * wa2) +
              fabsf(vb[0] * wb0 + vb[1] * wb1 + vb[2] * wb2) - 2.0f;
    }
    p[4] = nsum;
  }
  block_reduce<5>(p);
  if (threadIdx.x == 0) {
    atomicAdd(&acc[0], p[0]); atomicAdd(&acc[1], p[1]); atomicAdd(&acc[2], p[2]);
    atomicAdd(&acc[3], p[3]); atomicAdd(&acc[4], p[4]);
  }
}

__global__ __launch_bounds__(BLOCK) void point_kernel(
    const float* __restrict__ pred, const float* __restrict__ grad,
    float* __restrict__ acc, int M) {
  int i = blockIdx.x * blockDim.x + threadIdx.x;
  float p[2] = {0.f, 0.f};
  if (i < M) {
    p[0] = __expf(-100.0f * fabsf(pred[i]));
    float gx = grad[3 * i], gy = grad[3 * i + 1], gz = grad[3 * i + 2];
    p[1] = fabsf(sqrtf(gx * gx + gy * gy + gz * gz) - 1.0f);
  }
  block_reduce<2>(p);
  if (threadIdx.x == 0) {
    atomicAdd(&acc[5], p[0]); atomicAdd(&acc[1], p[1]);
  }
}

__global__ void finalize_acc(const float* __restrict__ acc, float* __restrict__ out,
                             int N, int M) {
  if (threadIdx.x == 0 && blockIdx.x == 0) {
    float sdf = acc[0] / (float)N;
    float eik = acc[1] / (float)(N + M);
    float morse = 0.5f * acc[2] / (3.0f * (float)N);
    float th = 0.5f * acc[3] / (3.0f * (float)N);
    float nb = acc[4] / ((float)N * (float)KVAL);
    float inter = acc[5] / (float)M;
    float loss = 7000.0f * sdf + 600.0f * inter + 50.0f * eik + 3.0f * morse +
                 10.0f * th + 30.0f * nb;
    out[0] = loss; out[1] = sdf; out[2] = inter; out[3] = eik;
    out[4] = morse; out[5] = th; out[6] = nb;
  }
}

extern "C" void kernel_launch(void* const* d_in, const int* in_sizes, int n_in,
                              void* d_out, int out_size, void* d_ws, size_t ws_size,
                              hipStream_t stream) {
  const float* mp    = (const float*)d_in[0];
  const float* npred = (const float*)d_in[1];
  const float* grad  = (const float*)d_in[2];
  const float* ngrad = (const float*)d_in[3];
  const float* H     = (const float*)d_in[4];
  const float* ngt   = (const float*)d_in[5];
  const float* theta = (const float*)d_in[6];
  const float* u     = (const float*)d_in[7];
  const float* v     = (const float*)d_in[8];
  const float* rot   = (const float*)d_in[9];
  const int*   nbr   = (const int*)d_in[10];
  float* out = (float*)d_out;

  int N = in_sizes[0];
  int M = in_sizes[1];
  int mx = (N > M) ? N : M;
  int nb1 = (mx + TILE - 1) / TILE;
  int nb2 = (N + TILE - 1) / TILE;

  size_t off_vavb = 256;
  size_t off_p1 = off_vavb + (size_t)N * 8;
  size_t off_p2 = off_p1 + (size_t)5 * nb1 * 4;
  size_t need = off_p2 + (size_t)nb2 * 4;

  if (ws_size >= need) {
    u2v* vavb8   = (u2v*)((char*)d_ws + off_vavb);
    float* part1 = (float*)((char*)d_ws + off_p1);
    float* part2 = (float*)((char*)d_ws + off_p2);
    s1_kernel<<<nb1, BLOCK, 0, stream>>>(
        theta, u, v, vavb8, N, npred, ngrad, mp, grad, H, ngt, part1, nb1, M);
    s3_kernel<<<nb2, BLOCK, 0, stream>>>(
        vavb8, rot, (const i2*)nbr, part2, N);
    finalize_fast<<<1, BLOCK, 0, stream>>>(part1, nb1, part2, nb2, out, N, M);
  } else {
    float* acc = (float*)d_ws;
    (void)hipMemsetAsync(acc, 0, 6 * sizeof(float), stream);
    vertex_kernel<<<(N + BLOCK - 1) / BLOCK, BLOCK, 0, stream>>>(
        mp, grad, H, ngt, theta, u, v, rot, nbr, acc, N);
    point_kernel<<<(M + BLOCK - 1) / BLOCK, BLOCK, 0, stream>>>(npred, ngrad, acc, M);
    finalize_acc<<<1, 64, 0, stream>>>(acc, out, N, M);
  }
}